// Round 1
// baseline (2034.491 us; speedup 1.0000x reference)
//
#include <hip/hip_runtime.h>
#include <math.h>

#define BB 4
#define TT 784
#define GG 28
#define EE 768
#define HDIM 3072
#define NHEAD 12
#define NLAYER 6
#define TTP 832           // padded token stride for vT

typedef short bfrag __attribute__((ext_vector_type(8)));   // 8 bf16 = 4 VGPRs
typedef float ffrag __attribute__((ext_vector_type(4)));   // 4 fp32 acc

__device__ __forceinline__ unsigned short f2b(float f) {
    union { float f; unsigned u; } v; v.f = f;
    unsigned r = v.u + 0x7FFF + ((v.u >> 16) & 1);         // RNE
    return (unsigned short)(r >> 16);
}

#define GLOAD_LDS16(g, l)                                                          \
    __builtin_amdgcn_global_load_lds(                                              \
        (const __attribute__((address_space(1))) void*)(g),                        \
        (__attribute__((address_space(3))) void*)(l), 16, 0, 0)

// bijective XCD swizzle (m204): consecutive tiles land on the same XCD's L2
__device__ __forceinline__ void swz_bxyz(int& bx, int& by, int& bz) {
    int gx = gridDim.x, gy = gridDim.y, gz = gridDim.z;
    int nwg = gx * gy * gz;
    int orig = blockIdx.x + gx * (blockIdx.y + gy * blockIdx.z);
    int q = nwg >> 3, r = nwg & 7;
    int xc = orig & 7, li = orig >> 3;
    int wg = (xc < r ? xc * (q + 1) : r * (q + 1) + (xc - r) * q) + li;
    bx = wg % gx;
    int t = wg / gx;
    by = t % gy;
    bz = t / gy;
}

// ---------------------------------------------------------------- reductions
__device__ __forceinline__ float block_reduce_sum256(float v, volatile float* sb) {
    #pragma unroll
    for (int m = 1; m < 64; m <<= 1) v += __shfl_xor(v, m, 64);
    int wave = threadIdx.x >> 6;
    if ((threadIdx.x & 63) == 0) sb[wave] = v;
    __syncthreads();
    return sb[0] + sb[1] + sb[2] + sb[3];
}

// ---------------------------------------------------------------- fp32 -> bf16 cast
__global__ __launch_bounds__(256) void cast_kernel(const float* __restrict__ s,
                                                   unsigned short* __restrict__ d, int n4) {
    int i = blockIdx.x * 256 + threadIdx.x;
    if (i >= n4) return;
    float4 v = ((const float4*)s)[i];
    ushort4 o;
    o.x = f2b(v.x); o.y = f2b(v.y); o.z = f2b(v.z); o.w = f2b(v.w);
    ((ushort4*)d)[i] = o;
}

// ---------------------------------------------------------------- fused per-layer weight cast
__global__ __launch_bounds__(256) void fused_cast_kernel(const float* __restrict__ iw,
                                                         const float* __restrict__ ow,
                                                         const float* __restrict__ W1,
                                                         const float* __restrict__ W2,
                                                         unsigned short* __restrict__ dq,
                                                         unsigned short* __restrict__ doo,
                                                         unsigned short* __restrict__ d1,
                                                         unsigned short* __restrict__ d2) {
    int i = blockIdx.x * 256 + threadIdx.x;
    const float* s; unsigned short* d; int k;
    if (i < 442368)            { s = iw;  d = dq;  k = i; }
    else if (i < 589824)       { s = ow;  d = doo; k = i - 442368; }
    else if (i < 1179648)      { s = W1;  d = d1;  k = i - 589824; }
    else if (i < 1769472)      { s = W2;  d = d2;  k = i - 1179648; }
    else return;
    float4 v = ((const float4*)s)[k];
    ushort4 o;
    o.x = f2b(v.x); o.y = f2b(v.y); o.z = f2b(v.z); o.w = f2b(v.w);
    ((ushort4*)d)[k] = o;
}

// ---------------------------------------------------------------- patchify -> bf16
__global__ __launch_bounds__(256) void patchify_kernel(const float* __restrict__ x,
                                                       unsigned short* __restrict__ P) {
    int idx = blockIdx.x * blockDim.x + threadIdx.x;
    const int total = BB * TT * EE;
    if (idx >= total) return;
    int k = idx % EE;
    int t = (idx / EE) % TT;
    int b = idx / (EE * TT);
    int c = k >> 8;
    int rem = k & 255;
    int p1 = rem >> 4;
    int p2 = rem & 15;
    int g1 = t / GG, g2 = t % GG;
    int hh = g1 * 16 + p1, ww = g2 * 16 + p2;
    P[idx] = f2b(x[((b * 448 + hh) * 448 + ww) * 3 + c]);
}

// ---------------------------------------------------------------- pos prefill
__global__ __launch_bounds__(256) void posfill_kernel(float* __restrict__ h,
                                                      const float* __restrict__ pos) {
    int idx = blockIdx.x * blockDim.x + threadIdx.x;
    const int total = BB * TT * EE;
    if (idx >= total) return;
    h[idx] = pos[idx % (TT * EE)];
}

// ---------------------------------------------------------------- layernorm
__global__ __launch_bounds__(256) void ln_kernel(const float* __restrict__ X,
                                                 const float* __restrict__ g,
                                                 const float* __restrict__ bt,
                                                 unsigned short* __restrict__ Yb,
                                                 float* Yf) {
    __shared__ float sb1[4];
    __shared__ float sb2[4];
    int row = blockIdx.x;
    int tid = threadIdx.x;
    const float* x = X + (size_t)row * EE;
    float v0 = x[tid], v1 = x[tid + 256], v2 = x[tid + 512];
    float s = block_reduce_sum256(v0 + v1 + v2, sb1);
    float mean = s * (1.0f / 768.0f);
    float d0 = v0 - mean, d1 = v1 - mean, d2 = v2 - mean;
    __syncthreads();
    float ss = block_reduce_sum256(d0 * d0 + d1 * d1 + d2 * d2, sb2);
    float rstd = rsqrtf(ss * (1.0f / 768.0f) + 1e-5f);
    float y0 = d0 * rstd * g[tid]       + bt[tid];
    float y1 = d1 * rstd * g[tid + 256] + bt[tid + 256];
    float y2 = d2 * rstd * g[tid + 512] + bt[tid + 512];
    unsigned short* yb = Yb + (size_t)row * EE;
    yb[tid] = f2b(y0); yb[tid + 256] = f2b(y1); yb[tid + 512] = f2b(y2);
    if (Yf) {
        float* yf = Yf + (size_t)row * EE;
        yf[tid] = y0; yf[tid + 256] = y1; yf[tid + 512] = y2;
    }
}

// ---------------------------------------------------------------- pipelined MFMA core
// BK=64, double-buffered LDS, raw s_barrier + counted vmcnt(8):
// STAGE(t+1) issued before compute(t); drained only at the NEXT iteration's
// vmcnt(8) -> load latency hides under 32 MFMA + 16 ds_read_b128.
// LDS layout [128 rows][64 k] with XOR-16B-block swizzle (source pre-swizzled,
// read XOR'd; rule #21 both-sides) -> bank-balanced ds_read_b128.
__device__ __forceinline__ void gemm_core(const unsigned short* __restrict__ A,
                                          const unsigned short* __restrict__ W,
                                          int M, int K, int m0, int n0,
                                          int kbeg, int nk,
                                          unsigned short (&As)[2][8192],
                                          unsigned short (&Ws)[2][8192],
                                          ffrag (&acc)[4][4]) {
    int tid = threadIdx.x;
    int wave = tid >> 6, lane = tid & 63;
    int cl = lane & 15, qd = lane >> 4;
    int sr8 = lane >> 3;          // row within 8-row group
    int sbk = lane & 7;           // 16B-block index; note cl&7 == sbk
    int ssc = (sbk ^ sr8) << 3;   // pre-swizzled source column (shorts)
    int mh = (wave & 1) << 6, nh = (wave >> 1) << 6;

    const unsigned short* Asrc[4];
    const unsigned short* Wsrc[4];
    #pragma unroll
    for (int i = 0; i < 4; i++) {
        int ar = m0 + (wave << 5) + (i << 3) + sr8;
        if (ar > M - 1) ar = M - 1;
        Asrc[i] = A + (size_t)ar * K + kbeg + ssc;
        int wr = n0 + (wave << 5) + (i << 3) + sr8;
        Wsrc[i] = W + (size_t)wr * K + kbeg + ssc;
    }
    unsigned short* lAw = &As[0][0] + wave * 2048;
    unsigned short* lWw = &Ws[0][0] + wave * 2048;
    int fo0 = (qd ^ sbk) << 3;         // k-half 0 swizzled read offset
    int fo1 = ((qd ^ sbk) ^ 4) << 3;   // k-half 1

    // prologue: stage tile 0 into buffer 0
    #pragma unroll
    for (int i = 0; i < 4; i++) {
        GLOAD_LDS16(Asrc[i], lAw + i * 512);
        GLOAD_LDS16(Wsrc[i], lWw + i * 512);
    }
    int cur = 0;
    for (int t = 0; t < nk; ++t) {
        if (t + 1 < nk) {
            int kn = (t + 1) << 6;
            unsigned short* dA = lAw + ((cur ^ 1) * 8192);
            unsigned short* dW = lWw + ((cur ^ 1) * 8192);
            #pragma unroll
            for (int i = 0; i < 4; i++) {
                GLOAD_LDS16(Asrc[i] + kn, dA + i * 512);
                GLOAD_LDS16(Wsrc[i] + kn, dW + i * 512);
            }
            asm volatile("s_waitcnt vmcnt(8)" ::: "memory");  // tile t done, t+1 in flight
        } else {
            asm volatile("s_waitcnt vmcnt(0)" ::: "memory");
        }
        __builtin_amdgcn_s_barrier();
        __builtin_amdgcn_sched_barrier(0);
        const unsigned short* Ab = As[cur];
        const unsigned short* Wb = Ws[cur];
        bfrag af0[4], af1[4], bf0[4], bf1[4];
        #pragma unroll
        for (int i = 0; i < 4; i++) {
            int ra = (mh + (i << 4) + cl) << 6;
            int rb = (nh + (i << 4) + cl) << 6;
            af0[i] = *(const bfrag*)&Ab[ra + fo0];
            af1[i] = *(const bfrag*)&Ab[ra + fo1];
            bf0[i] = *(const bfrag*)&Wb[rb + fo0];
            bf1[i] = *(const bfrag*)&Wb[rb + fo1];
        }
        #pragma unroll
        for (int i = 0; i < 4; i++)
            #pragma unroll
            for (int j = 0; j < 4; j++) {
                acc[i][j] = __builtin_amdgcn_mfma_f32_16x16x32_bf16(af0[i], bf0[j], acc[i][j], 0, 0, 0);
                acc[i][j] = __builtin_amdgcn_mfma_f32_16x16x32_bf16(af1[i], bf1[j], acc[i][j], 0, 0, 0);
            }
        __builtin_amdgcn_s_barrier();   // reads of buf[cur] done before it is restaged
        cur ^= 1;
    }
}

// ---------------------------------------------------------------- bf16 MFMA GEMM (generic)
__global__ __launch_bounds__(256) void gemm_bf16(const unsigned short* __restrict__ A,
                                                 const unsigned short* __restrict__ W,
                                                 const float* __restrict__ bias,
                                                 const float* R, float* C,
                                                 unsigned short* Cb,
                                                 int M, int N, int K, int act) {
    __shared__ unsigned short As[2][8192];
    __shared__ unsigned short Ws[2][8192];
    int bx, by, bz;
    swz_bxyz(bx, by, bz);
    int m0 = by << 7, n0 = bx << 7;

    ffrag acc[4][4] = {};
    gemm_core(A, W, M, K, m0, n0, 0, K >> 6, As, Ws, acc);

    int tid = threadIdx.x;
    int wave = tid >> 6, lane = tid & 63;
    int cl = lane & 15, qd = lane >> 4;
    int mh = (wave & 1) << 6, nh = (wave >> 1) << 6;

    #pragma unroll
    for (int j = 0; j < 4; j++) {
        int col = n0 + nh + (j << 4) + cl;
        float bv = bias[col];
        #pragma unroll
        for (int i = 0; i < 4; i++) {
            int row0 = m0 + mh + (i << 4) + (qd << 2);
            #pragma unroll
            for (int r = 0; r < 4; r++) {
                int row = row0 + r;
                if (row < M) {
                    float v = acc[i][j][r] + bv;
                    if (R) v += R[(size_t)row * N + col];
                    if (act) v = 0.5f * v * (1.0f + erff(v * 0.70710678118654752f));
                    if (C)  C[(size_t)row * N + col] = v;
                    if (Cb) Cb[(size_t)row * N + col] = f2b(v);
                }
            }
        }
    }
}

// ---------------------------------------------------------------- QKV GEMM: writes Q,K row-major + V transposed
__global__ __launch_bounds__(256) void gemm_qkv(const unsigned short* __restrict__ A,
                                                const unsigned short* __restrict__ W,
                                                const float* __restrict__ bias,
                                                unsigned short* __restrict__ Q,
                                                unsigned short* __restrict__ Kd,
                                                unsigned short* __restrict__ vT,
                                                int M, int N, int K) {
    __shared__ unsigned short As[2][8192];
    __shared__ unsigned short Ws[2][8192];
    int bx, by, bz;
    swz_bxyz(bx, by, bz);
    int m0 = by << 7, n0 = bx << 7;

    ffrag acc[4][4] = {};
    gemm_core(A, W, M, K, m0, n0, 0, K >> 6, As, Ws, acc);

    int tid = threadIdx.x;
    int wave = tid >> 6, lane = tid & 63;
    int cl = lane & 15, qd = lane >> 4;
    int mh = (wave & 1) << 6, nh = (wave >> 1) << 6;

    int ncb = n0 + nh;                        // 64-aligned col base for this wave
    if (ncb < 1536) {
        unsigned short* dst = (ncb < 768) ? Q : Kd;
        int cb = (ncb < 768) ? 0 : 768;
        #pragma unroll
        for (int j = 0; j < 4; j++) {
            int col = ncb + (j << 4) + cl;
            float bv = bias[col];
            #pragma unroll
            for (int i = 0; i < 4; i++) {
                int row0 = m0 + mh + (i << 4) + (qd << 2);
                #pragma unroll
                for (int r = 0; r < 4; r++) {
                    int row = row0 + r;
                    if (row < M)
                        dst[(size_t)row * EE + col - cb] = f2b(acc[i][j][r] + bv);
                }
            }
        }
    } else {
        int hh = (ncb - 1536) >> 6;           // uniform per wave
        #pragma unroll
        for (int i = 0; i < 4; i++) {
            int row0 = m0 + mh + (i << 4) + (qd << 2);
            #pragma unroll
            for (int r = 0; r < 4; r++) {
                int row = row0 + r;
                if (row < M) {
                    int b = row / TT;
                    int t = row - b * TT;
                    size_t vbase = ((size_t)(b * NHEAD + hh) * 64) * TTP + t;
                    #pragma unroll
                    for (int j = 0; j < 4; j++) {
                        int col = ncb + (j << 4) + cl;
                        vT[vbase + (size_t)((j << 4) + cl) * TTP] =
                            f2b(acc[i][j][r] + bias[col]);
                    }
                }
            }
        }
    }
}

// ---------------------------------------------------------------- split-K bf16 MFMA GEMM (atomic fp32)
__global__ __launch_bounds__(256) void gemm_bf16_sk(const unsigned short* __restrict__ A,
                                                    const unsigned short* __restrict__ W,
                                                    const float* __restrict__ bias,
                                                    float* C,
                                                    int M, int N, int K, int KC) {
    __shared__ unsigned short As[2][8192];
    __shared__ unsigned short Ws[2][8192];
    int bx, by, bz;
    swz_bxyz(bx, by, bz);
    int m0 = by << 7, n0 = bx << 7;
    int z = bz;
    int kbeg = z * KC;
    int kc2 = (kbeg + KC > K) ? (K - kbeg) : KC;

    ffrag acc[4][4] = {};
    gemm_core(A, W, M, K, m0, n0, kbeg, kc2 >> 6, As, Ws, acc);

    int tid = threadIdx.x;
    int wave = tid >> 6, lane = tid & 63;
    int cl = lane & 15, qd = lane >> 4;
    int mh = (wave & 1) << 6, nh = (wave >> 1) << 6;

    #pragma unroll
    for (int j = 0; j < 4; j++) {
        int col = n0 + nh + (j << 4) + cl;
        float bv = (z == 0) ? bias[col] : 0.0f;
        #pragma unroll
        for (int i = 0; i < 4; i++) {
            int row0 = m0 + mh + (i << 4) + (qd << 2);
            #pragma unroll
            for (int r = 0; r < 4; r++) {
                int row = row0 + r;
                if (row < M)
                    unsafeAtomicAdd(&C[(size_t)row * N + col], acc[i][j][r] + bv);
            }
        }
    }
}

// ---------------------------------------------------------------- MFMA flash attention v4
// Q,K: [B*T, 768] bf16; vT: [(b*12+h)*64+d][TTP] bf16; O: [B*T, 768] bf16.
// grid (13 q-tiles of 64, B*NH); block 256 = 4 waves, each wave 16 q-rows.
#define LP 72
#define SCL2 0.18033688011112042f   // 0.125 * log2(e)
__global__ __launch_bounds__(256) void attn_kernel(const unsigned short* __restrict__ Qg,
                                                   const unsigned short* __restrict__ Kg,
                                                   const unsigned short* __restrict__ vT,
                                                   unsigned short* __restrict__ O) {
    __shared__ unsigned short Ks[64 * LP];     // [k'][d]
    __shared__ unsigned short Vt[64 * LP];     // [d][k']
    __shared__ unsigned short Pb[64 * LP];     // [q_local][k'], wave-private rows
    int tid = threadIdx.x;
    int wave = tid >> 6, lane = tid & 63;
    int cl = lane & 15, qd = lane >> 4;
    int bh = blockIdx.y;
    int b = bh / NHEAD, hh = bh % NHEAD;
    int q0 = blockIdx.x * 64;
    int qw = q0 + wave * 16;

    int qrow = qw + cl;
    if (qrow > TT - 1) qrow = TT - 1;
    const unsigned short* qb = Qg + (size_t)(b * TT + qrow) * EE + hh * 64;
    bfrag qf0 = *(const bfrag*)(qb + (qd << 3));
    bfrag qf1 = *(const bfrag*)(qb + 32 + (qd << 3));

    ffrag o_acc[4] = {};
    float m_run[4], l_run[4];
    int qg_[4], qr_[4], qc_[4];
    #pragma unroll
    for (int r = 0; r < 4; r++) {
        qg_[r] = qw + (qd << 2) + r;
        qr_[r] = qg_[r] / GG;
        qc_[r] = qg_[r] % GG;
        m_run[r] = -1e30f; l_run[r] = 0.0f;
    }

    int kr[4], kc[4];
    #pragma unroll
    for (int j = 0; j < 4; j++) {
        int kg = j * 16 + cl;
        kr[j] = kg / GG; kc[j] = kg % GG;
    }

    const unsigned short* kbase = Kg + (size_t)b * TT * EE + hh * 64;
    const unsigned short* vbase = vT + (size_t)(b * NHEAD + hh) * 64 * TTP;
    int srow = tid >> 3;            // 0..31
    int scol = (tid & 7) << 3;      // 0..56

    for (int k0 = 0; k0 < 832; k0 += 64) {
        __syncthreads();
        #pragma unroll
        for (int it = 0; it < 2; it++) {
            int row = it * 32 + srow;
            int tok = k0 + row; if (tok > TT - 1) tok = TT - 1;
            *(bfrag*)&Ks[row * LP + scol] =
                *(const bfrag*)(kbase + (size_t)tok * EE + scol);
            *(bfrag*)&Vt[row * LP + scol] =
                *(const bfrag*)(vbase + (size_t)row * TTP + k0 + scol);
        }
        __syncthreads();

        // S = Q K^T
        ffrag sv[4];
        #pragma unroll
        for (int j = 0; j < 4; j++) {
            bfrag kf0 = *(const bfrag*)&Ks[(j * 16 + cl) * LP + (qd << 3)];
            bfrag kf1 = *(const bfrag*)&Ks[(j * 16 + cl) * LP + 32 + (qd << 3)];
            ffrag z = {0.f, 0.f, 0.f, 0.f};
            z = __builtin_amdgcn_mfma_f32_16x16x32_bf16(qf0, kf0, z, 0, 0, 0);
            z = __builtin_amdgcn_mfma_f32_16x16x32_bf16(qf1, kf1, z, 0, 0, 0);
            sv[j] = z;
        }

        // mask (LOCAL masked out); scale folded into exp2
        #pragma unroll
        for (int j = 0; j < 4; j++) {
            #pragma unroll
            for (int r = 0; r < 4; r++) {
                bool masked = (kr[j] > 27) ||
                              (abs(qr_[r] - kr[j]) <= 4 && abs(qc_[r] - kc[j]) <= 4);
                if (masked) sv[j][r] = -3.0e38f;
            }
        }

        // online softmax (rows live in 16-lane groups sharing qd)
        #pragma unroll
        for (int r = 0; r < 4; r++) {
            float mx = fmaxf(fmaxf(sv[0][r], sv[1][r]), fmaxf(sv[2][r], sv[3][r]));
            mx = fmaxf(mx, __shfl_xor(mx, 1, 64));
            mx = fmaxf(mx, __shfl_xor(mx, 2, 64));
            mx = fmaxf(mx, __shfl_xor(mx, 4, 64));
            mx = fmaxf(mx, __shfl_xor(mx, 8, 64));
            float m_new = fmaxf(m_run[r], mx);
            float alpha = exp2f((m_run[r] - m_new) * SCL2);
            float p0 = exp2f((sv[0][r] - m_new) * SCL2);
            float p1 = exp2f((sv[1][r] - m_new) * SCL2);
            float p2 = exp2f((sv[2][r] - m_new) * SCL2);
            float p3 = exp2f((sv[3][r] - m_new) * SCL2);
            float rs = (p0 + p1) + (p2 + p3);
            rs += __shfl_xor(rs, 1, 64);
            rs += __shfl_xor(rs, 2, 64);
            rs += __shfl_xor(rs, 4, 64);
            rs += __shfl_xor(rs, 8, 64);
            l_run[r] = l_run[r] * alpha + rs;
            m_run[r] = m_new;
            #pragma unroll
            for (int t = 0; t < 4; t++) o_acc[t][r] *= alpha;
            int prow = (wave * 16 + (qd << 2) + r) * LP;
            Pb[prow + 0 * 16 + cl] = f2b(p0);
            Pb[prow + 1 * 16 + cl] = f2b(p1);
            Pb[prow + 2 * 16 + cl] = f2b(p2);
            Pb[prow + 3 * 16 + cl] = f2b(p3);
        }
        // Pb rows are wave-private: drain this wave's LDS writes only
        asm volatile("s_waitcnt lgkmcnt(0)" ::: "memory");

        // O += P @ V
        bfrag pf0 = *(const bfrag*)&Pb[(wave * 16 + cl) * LP + (qd << 3)];
        bfrag pf1 = *(const bfrag*)&Pb[(wave * 16 + cl) * LP + 32 + (qd << 3)];
        #pragma unroll
        for (int t = 0; t < 4; t++) {
            bfrag vf0 = *(const bfrag*)&Vt[(t * 16 + cl) * LP + (qd << 3)];
            bfrag vf1 = *(const bfrag*)&Vt[(t * 16 + cl) * LP + 32 + (qd << 3)];
            o_acc[t] = __builtin_amdgcn_mfma_f32_16x16x32_bf16(pf0, vf0, o_acc[t], 0, 0, 0);
            o_acc[t] = __builtin_amdgcn_mfma_f32_16x16x32_bf16(pf1, vf1, o_acc[t], 0, 0, 0);
        }

        // advance kr/kc by 64 tokens (64 = 2*28 + 8)
        #pragma unroll
        for (int j = 0; j < 4; j++) {
            kc[j] += 8; kr[j] += 2;
            if (kc[j] >= GG) { kc[j] -= GG; kr[j] += 1; }
        }
    }

    #pragma unroll
    for (int r = 0; r < 4; r++) {
        if (qg_[r] < TT) {
            float inv = 1.0f / fmaxf(l_run[r], 1e-30f);
            #pragma unroll
            for (int t = 0; t < 4; t++)
                O[(size_t)(b * TT + qg_[r]) * EE + hh * 64 + t * 16 + cl] =
                    f2b(o_acc[t][r] * inv);
        }
    }
}

// ---------------------------------------------------------------- head
__global__ __launch_bounds__(256) void head_kernel(const float* __restrict__ Y,
                                                   const float* __restrict__ hw,
                                                   const float* __restrict__ hb,
                                                   const float* __restrict__ mean_,
                                                   const float* __restrict__ std_,
                                                   float* __restrict__ out) {
    __shared__ float sb[4];
    int row = blockIdx.x;
    int tid = threadIdx.x;
    const float* y = Y + (size_t)row * EE;
    float v = y[tid] * hw[tid] + y[tid + 256] * hw[tid + 256] + y[tid + 512] * hw[tid + 512];
    v = block_reduce_sum256(v, sb);
    if (tid == 0) {
        float logit = v + hb[0];
        float z = logit * std_[0] + mean_[0];
        float f = expf(z * 2.302585092994046f) - 1e-8f;
        f = fminf(fmaxf(f, 1e-15f), 1.0f);
        out[4 + row] = f;
    }
}

__global__ __launch_bounds__(256) void flux_sum_kernel(float* __restrict__ out) {
    __shared__ float sb[4];
    int b = blockIdx.x;
    int tid = threadIdx.x;
    const float* pf = out + 4 + (size_t)b * TT;
    float v = pf[tid] + pf[tid + 256] + pf[tid + 512];
    if (tid < TT - 768) v += pf[tid + 768];
    v = block_reduce_sum256(v, sb);
    if (tid == 0) out[b] = fmaxf(v, 1e-15f);
}

// ---------------------------------------------------------------- host
extern "C" void kernel_launch(void* const* d_in, const int* in_sizes, int n_in,
                              void* d_out, int out_size, void* d_ws, size_t ws_size,
                              hipStream_t stream) {
    const float* x        = (const float*)d_in[0];
    const float* sxr_mean = (const float*)d_in[1];
    const float* sxr_std  = (const float*)d_in[2];
    const float* input_w  = (const float*)d_in[3];
    const float* input_b  = (const float*)d_in[4];
    const float* pos_emb  = (const float*)d_in[5];
    const float* ln1_w    = (const float*)d_in[6];
    const float* ln1_b    = (const float*)d_in[7];
    const float* in_w     = (const float*)d_in[8];
    const float* in_b     = (const float*)d_in[9];
    const float* out_w    = (const float*)d_in[10];
    const float* out_b    = (const float*)d_in[11];
    const float* ln2_w    = (const float*)d_in[12];
    const float* ln2_b    = (const float*)d_in[13];
    const float* w1       = (const float*)d_in[14];
    const float* b1       = (const float*)d_in[15];
    const float* w2       = (const float*)d_in[16];
    const float* b2       = (const float*)d_in[17];
    const float* head_ln_w = (const float*)d_in[18];
    const float* head_ln_b = (const float*)d_in[19];
    const float* head_w   = (const float*)d_in[20];
    const float* head_b   = (const float*)d_in[21];
    float* out = (float*)d_out;

    const size_t NROW = (size_t)BB * TT;               // 3136
    const size_t NE   = NROW * EE;

    float* h   = (float*)d_ws;                         // [3136,768] f32
    float* y32 = h + NE;                               // [3136,768] f32 (head only)
    unsigned short* q_b   = (unsigned short*)(y32 + NE);   // [3136,768] bf16
    unsigned short* k_b   = q_b + NE;                      // [3136,768] bf16
    unsigned short* vT_b  = k_b + NE;                      // [48*64, 832] bf16
    unsigned short* y_b   = vT_b + (size_t)BB * NHEAD * 64 * TTP;
    unsigned short* o_b   = y_b + NE;
    unsigned short* mlp_b = o_b + NE;                  // [3136,3072] bf16
    unsigned short* wq_b  = mlp_b + NROW * HDIM;
    unsigned short* wo_b  = wq_b + (size_t)3 * EE * EE;
    unsigned short* w1_b  = wo_b + (size_t)EE * EE;
    unsigned short* w2_b  = w1_b + (size_t)HDIM * EE;

    const int tot = BB * TT * EE;
    const int GY = (int)((NROW + 127) / 128);          // 25

    patchify_kernel<<<(tot + 255) / 256, 256, 0, stream>>>(x, mlp_b);
    cast_kernel<<<(EE * EE / 4 + 255) / 256, 256, 0, stream>>>(input_w, wo_b, EE * EE / 4);
    posfill_kernel<<<(tot + 255) / 256, 256, 0, stream>>>(h, pos_emb);
    gemm_bf16_sk<<<dim3(EE / 128, GY, 4), 256, 0, stream>>>(
        mlp_b, wo_b, input_b, h, (int)NROW, EE, EE, 192);

    for (int l = 0; l < NLAYER; l++) {
        fused_cast_kernel<<<6912, 256, 0, stream>>>(
            in_w + (size_t)l * 3 * EE * EE, out_w + (size_t)l * EE * EE,
            w1 + (size_t)l * HDIM * EE, w2 + (size_t)l * EE * HDIM,
            wq_b, wo_b, w1_b, w2_b);

        ln_kernel<<<(int)NROW, 256, 0, stream>>>(h, ln1_w + l * EE, ln1_b + l * EE, y_b, nullptr);
        gemm_qkv<<<dim3(3 * EE / 128, GY), 256, 0, stream>>>(
            y_b, wq_b, in_b + (size_t)l * 3 * EE, q_b, k_b, vT_b,
            (int)NROW, 3 * EE, EE);
        attn_kernel<<<dim3(13, BB * NHEAD), 256, 0, stream>>>(q_b, k_b, vT_b, o_b);
        gemm_bf16_sk<<<dim3(EE / 128, GY, 4), 256, 0, stream>>>(
            o_b, wo_b, out_b + (size_t)l * EE, h, (int)NROW, EE, EE, 192);
        ln_kernel<<<(int)NROW, 256, 0, stream>>>(h, ln2_w + l * EE, ln2_b + l * EE, y_b, nullptr);
        gemm_bf16<<<dim3(HDIM / 128, GY), 256, 0, stream>>>(
            y_b, w1_b, b1 + (size_t)l * HDIM, nullptr, nullptr, mlp_b,
            (int)NROW, HDIM, EE, 1);
        gemm_bf16_sk<<<dim3(EE / 128, GY, 4), 256, 0, stream>>>(
            mlp_b, w2_b, b2 + (size_t)l * EE, h, (int)NROW, EE, HDIM, 768);
    }

    ln_kernel<<<(int)NROW, 256, 0, stream>>>(h, head_ln_w, head_ln_b, y_b, y32);
    head_kernel<<<(int)NROW, 256, 0, stream>>>(y32, head_w, head_b, sxr_mean, sxr_std, out);
    flux_sum_kernel<<<BB, 256, 0, stream>>>(out);
}

// Round 2
// 1687.959 us; speedup vs baseline: 1.2053x; 1.2053x over previous
//
#include <hip/hip_runtime.h>
#include <math.h>

#define BB 4
#define TT 784
#define GG 28
#define EE 768
#define HDIM 3072
#define NHEAD 12
#define NLAYER 6
#define TTP 832           // padded token stride for vT

typedef short bfrag __attribute__((ext_vector_type(8)));   // 8 bf16 = 4 VGPRs
typedef float ffrag __attribute__((ext_vector_type(4)));   // 4 fp32 acc

__device__ __forceinline__ unsigned short f2b(float f) {
    union { float f; unsigned u; } v; v.f = f;
    unsigned r = v.u + 0x7FFF + ((v.u >> 16) & 1);         // RNE
    return (unsigned short)(r >> 16);
}

#define GLOAD_LDS16(g, l)                                                          \
    __builtin_amdgcn_global_load_lds(                                              \
        (const __attribute__((address_space(1))) void*)(g),                        \
        (__attribute__((address_space(3))) void*)(l), 16, 0, 0)

// bijective XCD swizzle (m204): consecutive tiles land on the same XCD's L2
__device__ __forceinline__ void swz_bxyz(int& bx, int& by, int& bz) {
    int gx = gridDim.x, gy = gridDim.y, gz = gridDim.z;
    int nwg = gx * gy * gz;
    int orig = blockIdx.x + gx * (blockIdx.y + gy * blockIdx.z);
    int q = nwg >> 3, r = nwg & 7;
    int xc = orig & 7, li = orig >> 3;
    int wg = (xc < r ? xc * (q + 1) : r * (q + 1) + (xc - r) * q) + li;
    bx = wg % gx;
    int t = wg / gx;
    by = t % gy;
    bz = t / gy;
}

// ---------------------------------------------------------------- reductions
__device__ __forceinline__ float block_reduce_sum256(float v, volatile float* sb) {
    #pragma unroll
    for (int m = 1; m < 64; m <<= 1) v += __shfl_xor(v, m, 64);
    int wave = threadIdx.x >> 6;
    if ((threadIdx.x & 63) == 0) sb[wave] = v;
    __syncthreads();
    return sb[0] + sb[1] + sb[2] + sb[3];
}

// ---------------------------------------------------------------- fp32 -> bf16 cast
__global__ __launch_bounds__(256) void cast_kernel(const float* __restrict__ s,
                                                   unsigned short* __restrict__ d, int n4) {
    int i = blockIdx.x * 256 + threadIdx.x;
    if (i >= n4) return;
    float4 v = ((const float4*)s)[i];
    ushort4 o;
    o.x = f2b(v.x); o.y = f2b(v.y); o.z = f2b(v.z); o.w = f2b(v.w);
    ((ushort4*)d)[i] = o;
}

// ---------------------------------------------------------------- fused per-layer weight cast
__global__ __launch_bounds__(256) void fused_cast_kernel(const float* __restrict__ iw,
                                                         const float* __restrict__ ow,
                                                         const float* __restrict__ W1,
                                                         const float* __restrict__ W2,
                                                         unsigned short* __restrict__ dq,
                                                         unsigned short* __restrict__ doo,
                                                         unsigned short* __restrict__ d1,
                                                         unsigned short* __restrict__ d2) {
    int i = blockIdx.x * 256 + threadIdx.x;
    const float* s; unsigned short* d; int k;
    if (i < 442368)            { s = iw;  d = dq;  k = i; }
    else if (i < 589824)       { s = ow;  d = doo; k = i - 442368; }
    else if (i < 1179648)      { s = W1;  d = d1;  k = i - 589824; }
    else if (i < 1769472)      { s = W2;  d = d2;  k = i - 1179648; }
    else return;
    float4 v = ((const float4*)s)[k];
    ushort4 o;
    o.x = f2b(v.x); o.y = f2b(v.y); o.z = f2b(v.z); o.w = f2b(v.w);
    ((ushort4*)d)[k] = o;
}

// ---------------------------------------------------------------- patchify -> bf16
__global__ __launch_bounds__(256) void patchify_kernel(const float* __restrict__ x,
                                                       unsigned short* __restrict__ P) {
    int idx = blockIdx.x * blockDim.x + threadIdx.x;
    const int total = BB * TT * EE;
    if (idx >= total) return;
    int k = idx % EE;
    int t = (idx / EE) % TT;
    int b = idx / (EE * TT);
    int c = k >> 8;
    int rem = k & 255;
    int p1 = rem >> 4;
    int p2 = rem & 15;
    int g1 = t / GG, g2 = t % GG;
    int hh = g1 * 16 + p1, ww = g2 * 16 + p2;
    P[idx] = f2b(x[((b * 448 + hh) * 448 + ww) * 3 + c]);
}

// ---------------------------------------------------------------- pos prefill
__global__ __launch_bounds__(256) void posfill_kernel(float* __restrict__ h,
                                                      const float* __restrict__ pos) {
    int idx = blockIdx.x * blockDim.x + threadIdx.x;
    const int total = BB * TT * EE;
    if (idx >= total) return;
    h[idx] = pos[idx % (TT * EE)];
}

// ---------------------------------------------------------------- layernorm
__global__ __launch_bounds__(256) void ln_kernel(const float* __restrict__ X,
                                                 const float* __restrict__ g,
                                                 const float* __restrict__ bt,
                                                 unsigned short* __restrict__ Yb,
                                                 float* Yf) {
    __shared__ float sb1[4];
    __shared__ float sb2[4];
    int row = blockIdx.x;
    int tid = threadIdx.x;
    const float* x = X + (size_t)row * EE;
    float v0 = x[tid], v1 = x[tid + 256], v2 = x[tid + 512];
    float s = block_reduce_sum256(v0 + v1 + v2, sb1);
    float mean = s * (1.0f / 768.0f);
    float d0 = v0 - mean, d1 = v1 - mean, d2 = v2 - mean;
    __syncthreads();
    float ss = block_reduce_sum256(d0 * d0 + d1 * d1 + d2 * d2, sb2);
    float rstd = rsqrtf(ss * (1.0f / 768.0f) + 1e-5f);
    float y0 = d0 * rstd * g[tid]       + bt[tid];
    float y1 = d1 * rstd * g[tid + 256] + bt[tid + 256];
    float y2 = d2 * rstd * g[tid + 512] + bt[tid + 512];
    unsigned short* yb = Yb + (size_t)row * EE;
    yb[tid] = f2b(y0); yb[tid + 256] = f2b(y1); yb[tid + 512] = f2b(y2);
    if (Yf) {
        float* yf = Yf + (size_t)row * EE;
        yf[tid] = y0; yf[tid + 256] = y1; yf[tid + 512] = y2;
    }
}

// ---------------------------------------------------------------- pipelined MFMA core v2
// BK=32, TRIPLE-buffered LDS (48 KB total -> 3 blocks/CU), prefetch depth 2:
// stage(t+2) issued while computing tile t; counted vmcnt(8) keeps two stages
// (4 loads each) in flight -> ~2 K-steps of latency hiding, occupancy stays
// grid-limited. LDS rows are 64 B = 4x16B blocks, XOR-swizzled both-sides
// (pre-swizzled global source, XOR'd read) -> conflict-free ds_read_b128.
__device__ __forceinline__ void gemm_core(const unsigned short* __restrict__ A,
                                          const unsigned short* __restrict__ W,
                                          int M, int K, int m0, int n0,
                                          int kbeg, int nk,
                                          unsigned short* As,   // [3*4096]
                                          unsigned short* Ws,   // [3*4096]
                                          ffrag (&acc)[4][4]) {
    int tid = threadIdx.x;
    int wave = tid >> 6, lane = tid & 63;
    int cl = lane & 15, qd = lane >> 4;
    int sr  = lane >> 2;                 // staged row within 16-row group (0..15)
    int sbk = lane & 3;                  // 16B-block index within 64B row
    int ssc = (sbk ^ (sr & 3)) << 3;     // pre-swizzled source col (shorts)
    int mh = (wave & 1) << 6, nh = (wave >> 1) << 6;

    const unsigned short* Asrc0;
    const unsigned short* Asrc1;
    const unsigned short* Wsrc0;
    const unsigned short* Wsrc1;
    {
        int ar0 = m0 + (wave << 5) + sr;       if (ar0 > M - 1) ar0 = M - 1;
        int ar1 = m0 + (wave << 5) + 16 + sr;  if (ar1 > M - 1) ar1 = M - 1;
        Asrc0 = A + (size_t)ar0 * K + kbeg + ssc;
        Asrc1 = A + (size_t)ar1 * K + kbeg + ssc;
        int wr0 = n0 + (wave << 5) + sr;
        int wr1 = n0 + (wave << 5) + 16 + sr;
        Wsrc0 = W + (size_t)wr0 * K + kbeg + ssc;
        Wsrc1 = W + (size_t)wr1 * K + kbeg + ssc;
    }
    int dof0 = (wave << 10);            // wave's 32-row slice = 1024 shorts
    int dof1 = (wave << 10) + 512;
    int fo = (qd ^ (cl & 3)) << 3;      // swizzled read offset (shorts)

#define STAGE32(sa, sw, kk) do {                         \
        GLOAD_LDS16(Asrc0 + (kk), (sa) + dof0);          \
        GLOAD_LDS16(Asrc1 + (kk), (sa) + dof1);          \
        GLOAD_LDS16(Wsrc0 + (kk), (sw) + dof0);          \
        GLOAD_LDS16(Wsrc1 + (kk), (sw) + dof1);          \
    } while (0)

    unsigned short *a0 = As, *a1 = As + 4096, *a2 = As + 8192;
    unsigned short *w0 = Ws, *w1 = Ws + 4096, *w2 = Ws + 8192;

    STAGE32(a0, w0, 0);
    if (nk > 1) STAGE32(a1, w1, 32);

    for (int t = 0; t < nk; ++t) {
        if (t + 2 < nk) {
            STAGE32(a2, w2, (t + 2) << 5);
            asm volatile("s_waitcnt vmcnt(8)" ::: "memory");   // tile t done; t+1,t+2 in flight
        } else if (t + 1 < nk) {
            asm volatile("s_waitcnt vmcnt(4)" ::: "memory");   // tile t done; t+1 in flight
        } else {
            asm volatile("s_waitcnt vmcnt(0)" ::: "memory");
        }
        __builtin_amdgcn_s_barrier();
        __builtin_amdgcn_sched_barrier(0);

        bfrag af[4], bf[4];
        #pragma unroll
        for (int i = 0; i < 4; i++)
            af[i] = *(const bfrag*)&a0[((mh + (i << 4) + cl) << 5) + fo];
        #pragma unroll
        for (int j = 0; j < 4; j++)
            bf[j] = *(const bfrag*)&w0[((nh + (j << 4) + cl) << 5) + fo];
        #pragma unroll
        for (int i = 0; i < 4; i++)
            #pragma unroll
            for (int j = 0; j < 4; j++)
                acc[i][j] = __builtin_amdgcn_mfma_f32_16x16x32_bf16(af[i], bf[j], acc[i][j], 0, 0, 0);

        __builtin_amdgcn_s_barrier();   // all reads of a0/w0 done before restage
        unsigned short* tp;
        tp = a0; a0 = a1; a1 = a2; a2 = tp;
        tp = w0; w0 = w1; w1 = w2; w2 = tp;
    }
#undef STAGE32
}

// ---------------------------------------------------------------- bf16 MFMA GEMM (generic)
__global__ __launch_bounds__(256) void gemm_bf16(const unsigned short* __restrict__ A,
                                                 const unsigned short* __restrict__ W,
                                                 const float* __restrict__ bias,
                                                 const float* R, float* C,
                                                 unsigned short* Cb,
                                                 int M, int N, int K, int act) {
    __shared__ __align__(16) unsigned short As[3 * 4096];
    __shared__ __align__(16) unsigned short Ws[3 * 4096];
    int bx, by, bz;
    swz_bxyz(bx, by, bz);
    int m0 = by << 7, n0 = bx << 7;

    ffrag acc[4][4] = {};
    gemm_core(A, W, M, K, m0, n0, 0, K >> 5, As, Ws, acc);

    int tid = threadIdx.x;
    int wave = tid >> 6, lane = tid & 63;
    int cl = lane & 15, qd = lane >> 4;
    int mh = (wave & 1) << 6, nh = (wave >> 1) << 6;

    #pragma unroll
    for (int j = 0; j < 4; j++) {
        int col = n0 + nh + (j << 4) + cl;
        float bv = bias[col];
        #pragma unroll
        for (int i = 0; i < 4; i++) {
            int row0 = m0 + mh + (i << 4) + (qd << 2);
            #pragma unroll
            for (int r = 0; r < 4; r++) {
                int row = row0 + r;
                if (row < M) {
                    float v = acc[i][j][r] + bv;
                    if (R) v += R[(size_t)row * N + col];
                    if (act) v = 0.5f * v * (1.0f + erff(v * 0.70710678118654752f));
                    if (C)  C[(size_t)row * N + col] = v;
                    if (Cb) Cb[(size_t)row * N + col] = f2b(v);
                }
            }
        }
    }
}

// ---------------------------------------------------------------- QKV GEMM: writes Q,K row-major + V transposed
__global__ __launch_bounds__(256) void gemm_qkv(const unsigned short* __restrict__ A,
                                                const unsigned short* __restrict__ W,
                                                const float* __restrict__ bias,
                                                unsigned short* __restrict__ Q,
                                                unsigned short* __restrict__ Kd,
                                                unsigned short* __restrict__ vT,
                                                int M, int N, int K) {
    __shared__ __align__(16) unsigned short As[3 * 4096];
    __shared__ __align__(16) unsigned short Ws[3 * 4096];
    int bx, by, bz;
    swz_bxyz(bx, by, bz);
    int m0 = by << 7, n0 = bx << 7;

    ffrag acc[4][4] = {};
    gemm_core(A, W, M, K, m0, n0, 0, K >> 5, As, Ws, acc);

    int tid = threadIdx.x;
    int wave = tid >> 6, lane = tid & 63;
    int cl = lane & 15, qd = lane >> 4;
    int mh = (wave & 1) << 6, nh = (wave >> 1) << 6;

    int ncb = n0 + nh;                        // 64-aligned col base for this wave
    if (ncb < 1536) {
        unsigned short* dst = (ncb < 768) ? Q : Kd;
        int cb = (ncb < 768) ? 0 : 768;
        #pragma unroll
        for (int j = 0; j < 4; j++) {
            int col = ncb + (j << 4) + cl;
            float bv = bias[col];
            #pragma unroll
            for (int i = 0; i < 4; i++) {
                int row0 = m0 + mh + (i << 4) + (qd << 2);
                #pragma unroll
                for (int r = 0; r < 4; r++) {
                    int row = row0 + r;
                    if (row < M)
                        dst[(size_t)row * EE + col - cb] = f2b(acc[i][j][r] + bv);
                }
            }
        }
    } else {
        int hh = (ncb - 1536) >> 6;           // uniform per wave
        #pragma unroll
        for (int i = 0; i < 4; i++) {
            int row0 = m0 + mh + (i << 4) + (qd << 2);
            #pragma unroll
            for (int r = 0; r < 4; r++) {
                int row = row0 + r;
                if (row < M) {
                    int b = row / TT;
                    int t = row - b * TT;
                    size_t vbase = ((size_t)(b * NHEAD + hh) * 64) * TTP + t;
                    #pragma unroll
                    for (int j = 0; j < 4; j++) {
                        int col = ncb + (j << 4) + cl;
                        vT[vbase + (size_t)((j << 4) + cl) * TTP] =
                            f2b(acc[i][j][r] + bias[col]);
                    }
                }
            }
        }
    }
}

// ---------------------------------------------------------------- split-K bf16 MFMA GEMM (atomic fp32)
__global__ __launch_bounds__(256) void gemm_bf16_sk(const unsigned short* __restrict__ A,
                                                    const unsigned short* __restrict__ W,
                                                    const float* __restrict__ bias,
                                                    float* C,
                                                    int M, int N, int K, int KC) {
    __shared__ __align__(16) unsigned short As[3 * 4096];
    __shared__ __align__(16) unsigned short Ws[3 * 4096];
    int bx, by, bz;
    swz_bxyz(bx, by, bz);
    int m0 = by << 7, n0 = bx << 7;
    int z = bz;
    int kbeg = z * KC;
    int kc2 = (kbeg + KC > K) ? (K - kbeg) : KC;

    ffrag acc[4][4] = {};
    gemm_core(A, W, M, K, m0, n0, kbeg, kc2 >> 5, As, Ws, acc);

    int tid = threadIdx.x;
    int wave = tid >> 6, lane = tid & 63;
    int cl = lane & 15, qd = lane >> 4;
    int mh = (wave & 1) << 6, nh = (wave >> 1) << 6;

    #pragma unroll
    for (int j = 0; j < 4; j++) {
        int col = n0 + nh + (j << 4) + cl;
        float bv = (z == 0) ? bias[col] : 0.0f;
        #pragma unroll
        for (int i = 0; i < 4; i++) {
            int row0 = m0 + mh + (i << 4) + (qd << 2);
            #pragma unroll
            for (int r = 0; r < 4; r++) {
                int row = row0 + r;
                if (row < M)
                    unsafeAtomicAdd(&C[(size_t)row * N + col], acc[i][j][r] + bv);
            }
        }
    }
}

// ---------------------------------------------------------------- MFMA flash attention v4
// Q,K: [B*T, 768] bf16; vT: [(b*12+h)*64+d][TTP] bf16; O: [B*T, 768] bf16.
// grid (13 q-tiles of 64, B*NH); block 256 = 4 waves, each wave 16 q-rows.
#define LP 72
#define SCL2 0.18033688011112042f   // 0.125 * log2(e)
__global__ __launch_bounds__(256) void attn_kernel(const unsigned short* __restrict__ Qg,
                                                   const unsigned short* __restrict__ Kg,
                                                   const unsigned short* __restrict__ vT,
                                                   unsigned short* __restrict__ O) {
    __shared__ unsigned short Ks[64 * LP];     // [k'][d]
    __shared__ unsigned short Vt[64 * LP];     // [d][k']
    __shared__ unsigned short Pb[64 * LP];     // [q_local][k'], wave-private rows
    int tid = threadIdx.x;
    int wave = tid >> 6, lane = tid & 63;
    int cl = lane & 15, qd = lane >> 4;
    int bh = blockIdx.y;
    int b = bh / NHEAD, hh = bh % NHEAD;
    int q0 = blockIdx.x * 64;
    int qw = q0 + wave * 16;

    int qrow = qw + cl;
    if (qrow > TT - 1) qrow = TT - 1;
    const unsigned short* qb = Qg + (size_t)(b * TT + qrow) * EE + hh * 64;
    bfrag qf0 = *(const bfrag*)(qb + (qd << 3));
    bfrag qf1 = *(const bfrag*)(qb + 32 + (qd << 3));

    ffrag o_acc[4] = {};
    float m_run[4], l_run[4];
    int qg_[4], qr_[4], qc_[4];
    #pragma unroll
    for (int r = 0; r < 4; r++) {
        qg_[r] = qw + (qd << 2) + r;
        qr_[r] = qg_[r] / GG;
        qc_[r] = qg_[r] % GG;
        m_run[r] = -1e30f; l_run[r] = 0.0f;
    }

    int kr[4], kc[4];
    #pragma unroll
    for (int j = 0; j < 4; j++) {
        int kg = j * 16 + cl;
        kr[j] = kg / GG; kc[j] = kg % GG;
    }

    const unsigned short* kbase = Kg + (size_t)b * TT * EE + hh * 64;
    const unsigned short* vbase = vT + (size_t)(b * NHEAD + hh) * 64 * TTP;
    int srow = tid >> 3;            // 0..31
    int scol = (tid & 7) << 3;      // 0..56

    for (int k0 = 0; k0 < 832; k0 += 64) {
        __syncthreads();
        #pragma unroll
        for (int it = 0; it < 2; it++) {
            int row = it * 32 + srow;
            int tok = k0 + row; if (tok > TT - 1) tok = TT - 1;
            *(bfrag*)&Ks[row * LP + scol] =
                *(const bfrag*)(kbase + (size_t)tok * EE + scol);
            *(bfrag*)&Vt[row * LP + scol] =
                *(const bfrag*)(vbase + (size_t)row * TTP + k0 + scol);
        }
        __syncthreads();

        // S = Q K^T
        ffrag sv[4];
        #pragma unroll
        for (int j = 0; j < 4; j++) {
            bfrag kf0 = *(const bfrag*)&Ks[(j * 16 + cl) * LP + (qd << 3)];
            bfrag kf1 = *(const bfrag*)&Ks[(j * 16 + cl) * LP + 32 + (qd << 3)];
            ffrag z = {0.f, 0.f, 0.f, 0.f};
            z = __builtin_amdgcn_mfma_f32_16x16x32_bf16(qf0, kf0, z, 0, 0, 0);
            z = __builtin_amdgcn_mfma_f32_16x16x32_bf16(qf1, kf1, z, 0, 0, 0);
            sv[j] = z;
        }

        // mask (LOCAL masked out); scale folded into exp2
        #pragma unroll
        for (int j = 0; j < 4; j++) {
            #pragma unroll
            for (int r = 0; r < 4; r++) {
                bool masked = (kr[j] > 27) ||
                              (abs(qr_[r] - kr[j]) <= 4 && abs(qc_[r] - kc[j]) <= 4);
                if (masked) sv[j][r] = -3.0e38f;
            }
        }

        // online softmax (rows live in 16-lane groups sharing qd)
        #pragma unroll
        for (int r = 0; r < 4; r++) {
            float mx = fmaxf(fmaxf(sv[0][r], sv[1][r]), fmaxf(sv[2][r], sv[3][r]));
            mx = fmaxf(mx, __shfl_xor(mx, 1, 64));
            mx = fmaxf(mx, __shfl_xor(mx, 2, 64));
            mx = fmaxf(mx, __shfl_xor(mx, 4, 64));
            mx = fmaxf(mx, __shfl_xor(mx, 8, 64));
            float m_new = fmaxf(m_run[r], mx);
            float alpha = exp2f((m_run[r] - m_new) * SCL2);
            float p0 = exp2f((sv[0][r] - m_new) * SCL2);
            float p1 = exp2f((sv[1][r] - m_new) * SCL2);
            float p2 = exp2f((sv[2][r] - m_new) * SCL2);
            float p3 = exp2f((sv[3][r] - m_new) * SCL2);
            float rs = (p0 + p1) + (p2 + p3);
            rs += __shfl_xor(rs, 1, 64);
            rs += __shfl_xor(rs, 2, 64);
            rs += __shfl_xor(rs, 4, 64);
            rs += __shfl_xor(rs, 8, 64);
            l_run[r] = l_run[r] * alpha + rs;
            m_run[r] = m_new;
            #pragma unroll
            for (int t = 0; t < 4; t++) o_acc[t][r] *= alpha;
            int prow = (wave * 16 + (qd << 2) + r) * LP;
            Pb[prow + 0 * 16 + cl] = f2b(p0);
            Pb[prow + 1 * 16 + cl] = f2b(p1);
            Pb[prow + 2 * 16 + cl] = f2b(p2);
            Pb[prow + 3 * 16 + cl] = f2b(p3);
        }
        // Pb rows are wave-private: drain this wave's LDS writes only
        asm volatile("s_waitcnt lgkmcnt(0)" ::: "memory");

        // O += P @ V
        bfrag pf0 = *(const bfrag*)&Pb[(wave * 16 + cl) * LP + (qd << 3)];
        bfrag pf1 = *(const bfrag*)&Pb[(wave * 16 + cl) * LP + 32 + (qd << 3)];
        #pragma unroll
        for (int t = 0; t < 4; t++) {
            bfrag vf0 = *(const bfrag*)&Vt[(t * 16 + cl) * LP + (qd << 3)];
            bfrag vf1 = *(const bfrag*)&Vt[(t * 16 + cl) * LP + 32 + (qd << 3)];
            o_acc[t] = __builtin_amdgcn_mfma_f32_16x16x32_bf16(pf0, vf0, o_acc[t], 0, 0, 0);
            o_acc[t] = __builtin_amdgcn_mfma_f32_16x16x32_bf16(pf1, vf1, o_acc[t], 0, 0, 0);
        }

        // advance kr/kc by 64 tokens (64 = 2*28 + 8)
        #pragma unroll
        for (int j = 0; j < 4; j++) {
            kc[j] += 8; kr[j] += 2;
            if (kc[j] >= GG) { kc[j] -= GG; kr[j] += 1; }
        }
    }

    #pragma unroll
    for (int r = 0; r < 4; r++) {
        if (qg_[r] < TT) {
            float inv = 1.0f / fmaxf(l_run[r], 1e-30f);
            #pragma unroll
            for (int t = 0; t < 4; t++)
                O[(size_t)(b * TT + qg_[r]) * EE + hh * 64 + t * 16 + cl] =
                    f2b(o_acc[t][r] * inv);
        }
    }
}

// ---------------------------------------------------------------- head
__global__ __launch_bounds__(256) void head_kernel(const float* __restrict__ Y,
                                                   const float* __restrict__ hw,
                                                   const float* __restrict__ hb,
                                                   const float* __restrict__ mean_,
                                                   const float* __restrict__ std_,
                                                   float* __restrict__ out) {
    __shared__ float sb[4];
    int row = blockIdx.x;
    int tid = threadIdx.x;
    const float* y = Y + (size_t)row * EE;
    float v = y[tid] * hw[tid] + y[tid + 256] * hw[tid + 256] + y[tid + 512] * hw[tid + 512];
    v = block_reduce_sum256(v, sb);
    if (tid == 0) {
        float logit = v + hb[0];
        float z = logit * std_[0] + mean_[0];
        float f = expf(z * 2.302585092994046f) - 1e-8f;
        f = fminf(fmaxf(f, 1e-15f), 1.0f);
        out[4 + row] = f;
    }
}

__global__ __launch_bounds__(256) void flux_sum_kernel(float* __restrict__ out) {
    __shared__ float sb[4];
    int b = blockIdx.x;
    int tid = threadIdx.x;
    const float* pf = out + 4 + (size_t)b * TT;
    float v = pf[tid] + pf[tid + 256] + pf[tid + 512];
    if (tid < TT - 768) v += pf[tid + 768];
    v = block_reduce_sum256(v, sb);
    if (tid == 0) out[b] = fmaxf(v, 1e-15f);
}

// ---------------------------------------------------------------- host
extern "C" void kernel_launch(void* const* d_in, const int* in_sizes, int n_in,
                              void* d_out, int out_size, void* d_ws, size_t ws_size,
                              hipStream_t stream) {
    const float* x        = (const float*)d_in[0];
    const float* sxr_mean = (const float*)d_in[1];
    const float* sxr_std  = (const float*)d_in[2];
    const float* input_w  = (const float*)d_in[3];
    const float* input_b  = (const float*)d_in[4];
    const float* pos_emb  = (const float*)d_in[5];
    const float* ln1_w    = (const float*)d_in[6];
    const float* ln1_b    = (const float*)d_in[7];
    const float* in_w     = (const float*)d_in[8];
    const float* in_b     = (const float*)d_in[9];
    const float* out_w    = (const float*)d_in[10];
    const float* out_b    = (const float*)d_in[11];
    const float* ln2_w    = (const float*)d_in[12];
    const float* ln2_b    = (const float*)d_in[13];
    const float* w1       = (const float*)d_in[14];
    const float* b1       = (const float*)d_in[15];
    const float* w2       = (const float*)d_in[16];
    const float* b2       = (const float*)d_in[17];
    const float* head_ln_w = (const float*)d_in[18];
    const float* head_ln_b = (const float*)d_in[19];
    const float* head_w   = (const float*)d_in[20];
    const float* head_b   = (const float*)d_in[21];
    float* out = (float*)d_out;

    const size_t NROW = (size_t)BB * TT;               // 3136
    const size_t NE   = NROW * EE;

    float* h   = (float*)d_ws;                         // [3136,768] f32
    float* y32 = h + NE;                               // [3136,768] f32 (head only)
    unsigned short* q_b   = (unsigned short*)(y32 + NE);   // [3136,768] bf16
    unsigned short* k_b   = q_b + NE;                      // [3136,768] bf16
    unsigned short* vT_b  = k_b + NE;                      // [48*64, 832] bf16
    unsigned short* y_b   = vT_b + (size_t)BB * NHEAD * 64 * TTP;
    unsigned short* o_b   = y_b + NE;
    unsigned short* mlp_b = o_b + NE;                  // [3136,3072] bf16
    unsigned short* wq_b  = mlp_b + NROW * HDIM;
    unsigned short* wo_b  = wq_b + (size_t)3 * EE * EE;
    unsigned short* w1_b  = wo_b + (size_t)EE * EE;
    unsigned short* w2_b  = w1_b + (size_t)HDIM * EE;

    const int tot = BB * TT * EE;
    const int GY = (int)((NROW + 127) / 128);          // 25

    patchify_kernel<<<(tot + 255) / 256, 256, 0, stream>>>(x, mlp_b);
    cast_kernel<<<(EE * EE / 4 + 255) / 256, 256, 0, stream>>>(input_w, wo_b, EE * EE / 4);
    posfill_kernel<<<(tot + 255) / 256, 256, 0, stream>>>(h, pos_emb);
    gemm_bf16_sk<<<dim3(EE / 128, GY, 4), 256, 0, stream>>>(
        mlp_b, wo_b, input_b, h, (int)NROW, EE, EE, 192);

    for (int l = 0; l < NLAYER; l++) {
        fused_cast_kernel<<<6912, 256, 0, stream>>>(
            in_w + (size_t)l * 3 * EE * EE, out_w + (size_t)l * EE * EE,
            w1 + (size_t)l * HDIM * EE, w2 + (size_t)l * EE * HDIM,
            wq_b, wo_b, w1_b, w2_b);

        ln_kernel<<<(int)NROW, 256, 0, stream>>>(h, ln1_w + l * EE, ln1_b + l * EE, y_b, nullptr);
        gemm_qkv<<<dim3(3 * EE / 128, GY), 256, 0, stream>>>(
            y_b, wq_b, in_b + (size_t)l * 3 * EE, q_b, k_b, vT_b,
            (int)NROW, 3 * EE, EE);
        attn_kernel<<<dim3(13, BB * NHEAD), 256, 0, stream>>>(q_b, k_b, vT_b, o_b);
        gemm_bf16_sk<<<dim3(EE / 128, GY, 4), 256, 0, stream>>>(
            o_b, wo_b, out_b + (size_t)l * EE, h, (int)NROW, EE, EE, 192);
        ln_kernel<<<(int)NROW, 256, 0, stream>>>(h, ln2_w + l * EE, ln2_b + l * EE, y_b, nullptr);
        gemm_bf16<<<dim3(HDIM / 128, GY), 256, 0, stream>>>(
            y_b, w1_b, b1 + (size_t)l * HDIM, nullptr, nullptr, mlp_b,
            (int)NROW, HDIM, EE, 1);
        gemm_bf16_sk<<<dim3(EE / 128, GY, 4), 256, 0, stream>>>(
            mlp_b, w2_b, b2 + (size_t)l * EE, h, (int)NROW, EE, HDIM, 768);
    }

    ln_kernel<<<(int)NROW, 256, 0, stream>>>(h, head_ln_w, head_ln_b, y_b, y32);
    head_kernel<<<(int)NROW, 256, 0, stream>>>(y32, head_w, head_b, sxr_mean, sxr_std, out);
    flux_sum_kernel<<<BB, 256, 0, stream>>>(out);
}

// Round 3
// 1583.305 us; speedup vs baseline: 1.2850x; 1.0661x over previous
//
#include <hip/hip_runtime.h>
#include <math.h>

#define BB 4
#define TT 784
#define GG 28
#define EE 768
#define HDIM 3072
#define NHEAD 12
#define NLAYER 6
#define TTP 832           // padded token stride for vT

typedef short bfrag __attribute__((ext_vector_type(8)));   // 8 bf16 = 4 VGPRs
typedef float ffrag __attribute__((ext_vector_type(4)));   // 4 fp32 acc

__device__ __forceinline__ unsigned short f2b(float f) {
    union { float f; unsigned u; } v; v.f = f;
    unsigned r = v.u + 0x7FFF + ((v.u >> 16) & 1);         // RNE
    return (unsigned short)(r >> 16);
}

__device__ __forceinline__ float fexp2(float x) {          // raw v_exp_f32 (2^x)
    float r; asm("v_exp_f32 %0, %1" : "=v"(r) : "v"(x)); return r;
}
__device__ __forceinline__ float frcp(float x) {           // raw v_rcp_f32
    float r; asm("v_rcp_f32 %0, %1" : "=v"(r) : "v"(x)); return r;
}

#define GLOAD_LDS16(g, l)                                                          \
    __builtin_amdgcn_global_load_lds(                                              \
        (const __attribute__((address_space(1))) void*)(g),                        \
        (__attribute__((address_space(3))) void*)(l), 16, 0, 0)

// bijective XCD swizzle (m204): consecutive tiles land on the same XCD's L2
__device__ __forceinline__ void swz_bxyz(int& bx, int& by, int& bz) {
    int gx = gridDim.x, gy = gridDim.y, gz = gridDim.z;
    int nwg = gx * gy * gz;
    int orig = blockIdx.x + gx * (blockIdx.y + gy * blockIdx.z);
    int q = nwg >> 3, r = nwg & 7;
    int xc = orig & 7, li = orig >> 3;
    int wg = (xc < r ? xc * (q + 1) : r * (q + 1) + (xc - r) * q) + li;
    bx = wg % gx;
    int t = wg / gx;
    by = t % gy;
    bz = t / gy;
}

// ---------------------------------------------------------------- reductions
__device__ __forceinline__ float block_reduce_sum256(float v, volatile float* sb) {
    #pragma unroll
    for (int m = 1; m < 64; m <<= 1) v += __shfl_xor(v, m, 64);
    int wave = threadIdx.x >> 6;
    if ((threadIdx.x & 63) == 0) sb[wave] = v;
    __syncthreads();
    return sb[0] + sb[1] + sb[2] + sb[3];
}

// ---------------------------------------------------------------- fp32 -> bf16 cast
__global__ __launch_bounds__(256) void cast_kernel(const float* __restrict__ s,
                                                   unsigned short* __restrict__ d, int n4) {
    int i = blockIdx.x * 256 + threadIdx.x;
    if (i >= n4) return;
    float4 v = ((const float4*)s)[i];
    ushort4 o;
    o.x = f2b(v.x); o.y = f2b(v.y); o.z = f2b(v.z); o.w = f2b(v.w);
    ((ushort4*)d)[i] = o;
}

// ---------------------------------------------------------------- fused per-layer weight cast
__global__ __launch_bounds__(256) void fused_cast_kernel(const float* __restrict__ iw,
                                                         const float* __restrict__ ow,
                                                         const float* __restrict__ W1,
                                                         const float* __restrict__ W2,
                                                         unsigned short* __restrict__ dq,
                                                         unsigned short* __restrict__ doo,
                                                         unsigned short* __restrict__ d1,
                                                         unsigned short* __restrict__ d2) {
    int i = blockIdx.x * 256 + threadIdx.x;
    const float* s; unsigned short* d; int k;
    if (i < 442368)            { s = iw;  d = dq;  k = i; }
    else if (i < 589824)       { s = ow;  d = doo; k = i - 442368; }
    else if (i < 1179648)      { s = W1;  d = d1;  k = i - 589824; }
    else if (i < 1769472)      { s = W2;  d = d2;  k = i - 1179648; }
    else return;
    float4 v = ((const float4*)s)[k];
    ushort4 o;
    o.x = f2b(v.x); o.y = f2b(v.y); o.z = f2b(v.z); o.w = f2b(v.w);
    ((ushort4*)d)[k] = o;
}

// ---------------------------------------------------------------- patchify -> bf16
__global__ __launch_bounds__(256) void patchify_kernel(const float* __restrict__ x,
                                                       unsigned short* __restrict__ P) {
    int idx = blockIdx.x * blockDim.x + threadIdx.x;
    const int total = BB * TT * EE;
    if (idx >= total) return;
    int k = idx % EE;
    int t = (idx / EE) % TT;
    int b = idx / (EE * TT);
    int c = k >> 8;
    int rem = k & 255;
    int p1 = rem >> 4;
    int p2 = rem & 15;
    int g1 = t / GG, g2 = t % GG;
    int hh = g1 * 16 + p1, ww = g2 * 16 + p2;
    P[idx] = f2b(x[((b * 448 + hh) * 448 + ww) * 3 + c]);
}

// ---------------------------------------------------------------- pos prefill
__global__ __launch_bounds__(256) void posfill_kernel(float* __restrict__ h,
                                                      const float* __restrict__ pos) {
    int idx = blockIdx.x * blockDim.x + threadIdx.x;
    const int total = BB * TT * EE;
    if (idx >= total) return;
    h[idx] = pos[idx % (TT * EE)];
}

// ---------------------------------------------------------------- local-window mask bit table
// mtab[row*13 + t] bit i = token (t*64+i) masked for query row (incl. padding >=784)
__global__ __launch_bounds__(256) void mask_build_kernel(unsigned long long* __restrict__ mt) {
    int idx = blockIdx.x * 256 + threadIdx.x;
    if (idx >= TT * 13) return;
    int row = idx / 13, t = idx % 13;
    int qr = row / GG, qc = row % GG;
    unsigned long long bits = 0;
    for (int i = 0; i < 64; i++) {
        int k = t * 64 + i;
        bool m;
        if (k >= TT) m = true;
        else {
            int kr2 = k / GG, kc2 = k % GG;
            m = (abs(qr - kr2) <= 4) && (abs(qc - kc2) <= 4);
        }
        if (m) bits |= (1ull << i);
    }
    mt[idx] = bits;
}

// ---------------------------------------------------------------- layernorm
__global__ __launch_bounds__(256) void ln_kernel(const float* __restrict__ X,
                                                 const float* __restrict__ g,
                                                 const float* __restrict__ bt,
                                                 unsigned short* __restrict__ Yb,
                                                 float* Yf) {
    __shared__ float sb1[4];
    __shared__ float sb2[4];
    int row = blockIdx.x;
    int tid = threadIdx.x;
    const float* x = X + (size_t)row * EE;
    float v0 = x[tid], v1 = x[tid + 256], v2 = x[tid + 512];
    float s = block_reduce_sum256(v0 + v1 + v2, sb1);
    float mean = s * (1.0f / 768.0f);
    float d0 = v0 - mean, d1 = v1 - mean, d2 = v2 - mean;
    __syncthreads();
    float ss = block_reduce_sum256(d0 * d0 + d1 * d1 + d2 * d2, sb2);
    float rstd = rsqrtf(ss * (1.0f / 768.0f) + 1e-5f);
    float y0 = d0 * rstd * g[tid]       + bt[tid];
    float y1 = d1 * rstd * g[tid + 256] + bt[tid + 256];
    float y2 = d2 * rstd * g[tid + 512] + bt[tid + 512];
    unsigned short* yb = Yb + (size_t)row * EE;
    yb[tid] = f2b(y0); yb[tid + 256] = f2b(y1); yb[tid + 512] = f2b(y2);
    if (Yf) {
        float* yf = Yf + (size_t)row * EE;
        yf[tid] = y0; yf[tid + 256] = y1; yf[tid + 512] = y2;
    }
}

// ---------------------------------------------------------------- pipelined MFMA core v2
// BK=32, TRIPLE-buffered LDS (48 KB total -> 3 blocks/CU), prefetch depth 2
__device__ __forceinline__ void gemm_core(const unsigned short* __restrict__ A,
                                          const unsigned short* __restrict__ W,
                                          int M, int K, int m0, int n0,
                                          int kbeg, int nk,
                                          unsigned short* As,   // [3*4096]
                                          unsigned short* Ws,   // [3*4096]
                                          ffrag (&acc)[4][4]) {
    int tid = threadIdx.x;
    int wave = tid >> 6, lane = tid & 63;
    int cl = lane & 15, qd = lane >> 4;
    int sr  = lane >> 2;                 // staged row within 16-row group (0..15)
    int sbk = lane & 3;                  // 16B-block index within 64B row
    int ssc = (sbk ^ (sr & 3)) << 3;     // pre-swizzled source col (shorts)
    int mh = (wave & 1) << 6, nh = (wave >> 1) << 6;

    const unsigned short* Asrc0;
    const unsigned short* Asrc1;
    const unsigned short* Wsrc0;
    const unsigned short* Wsrc1;
    {
        int ar0 = m0 + (wave << 5) + sr;       if (ar0 > M - 1) ar0 = M - 1;
        int ar1 = m0 + (wave << 5) + 16 + sr;  if (ar1 > M - 1) ar1 = M - 1;
        Asrc0 = A + (size_t)ar0 * K + kbeg + ssc;
        Asrc1 = A + (size_t)ar1 * K + kbeg + ssc;
        int wr0 = n0 + (wave << 5) + sr;
        int wr1 = n0 + (wave << 5) + 16 + sr;
        Wsrc0 = W + (size_t)wr0 * K + kbeg + ssc;
        Wsrc1 = W + (size_t)wr1 * K + kbeg + ssc;
    }
    int dof0 = (wave << 10);            // wave's 32-row slice = 1024 shorts
    int dof1 = (wave << 10) + 512;
    int fo = (qd ^ (cl & 3)) << 3;      // swizzled read offset (shorts)

#define STAGE32(sa, sw, kk) do {                         \
        GLOAD_LDS16(Asrc0 + (kk), (sa) + dof0);          \
        GLOAD_LDS16(Asrc1 + (kk), (sa) + dof1);          \
        GLOAD_LDS16(Wsrc0 + (kk), (sw) + dof0);          \
        GLOAD_LDS16(Wsrc1 + (kk), (sw) + dof1);          \
    } while (0)

    unsigned short *a0 = As, *a1 = As + 4096, *a2 = As + 8192;
    unsigned short *w0 = Ws, *w1 = Ws + 4096, *w2 = Ws + 8192;

    STAGE32(a0, w0, 0);
    if (nk > 1) STAGE32(a1, w1, 32);

    for (int t = 0; t < nk; ++t) {
        if (t + 2 < nk) {
            STAGE32(a2, w2, (t + 2) << 5);
            asm volatile("s_waitcnt vmcnt(8)" ::: "memory");   // tile t done; t+1,t+2 in flight
        } else if (t + 1 < nk) {
            asm volatile("s_waitcnt vmcnt(4)" ::: "memory");   // tile t done; t+1 in flight
        } else {
            asm volatile("s_waitcnt vmcnt(0)" ::: "memory");
        }
        __builtin_amdgcn_s_barrier();
        __builtin_amdgcn_sched_barrier(0);

        bfrag af[4], bf[4];
        #pragma unroll
        for (int i = 0; i < 4; i++)
            af[i] = *(const bfrag*)&a0[((mh + (i << 4) + cl) << 5) + fo];
        #pragma unroll
        for (int j = 0; j < 4; j++)
            bf[j] = *(const bfrag*)&w0[((nh + (j << 4) + cl) << 5) + fo];
        #pragma unroll
        for (int i = 0; i < 4; i++)
            #pragma unroll
            for (int j = 0; j < 4; j++)
                acc[i][j] = __builtin_amdgcn_mfma_f32_16x16x32_bf16(af[i], bf[j], acc[i][j], 0, 0, 0);

        __builtin_amdgcn_s_barrier();   // all reads of a0/w0 done before restage
        unsigned short* tp;
        tp = a0; a0 = a1; a1 = a2; a2 = tp;
        tp = w0; w0 = w1; w1 = w2; w2 = tp;
    }
#undef STAGE32
}

// ---------------------------------------------------------------- bf16 MFMA GEMM (generic)
__global__ __launch_bounds__(256) void gemm_bf16(const unsigned short* __restrict__ A,
                                                 const unsigned short* __restrict__ W,
                                                 const float* __restrict__ bias,
                                                 const float* R, float* C,
                                                 unsigned short* Cb,
                                                 int M, int N, int K, int act) {
    __shared__ __align__(16) unsigned short As[3 * 4096];
    __shared__ __align__(16) unsigned short Ws[3 * 4096];
    int bx, by, bz;
    swz_bxyz(bx, by, bz);
    int m0 = by << 7, n0 = bx << 7;

    ffrag acc[4][4] = {};
    gemm_core(A, W, M, K, m0, n0, 0, K >> 5, As, Ws, acc);

    int tid = threadIdx.x;
    int wave = tid >> 6, lane = tid & 63;
    int cl = lane & 15, qd = lane >> 4;
    int mh = (wave & 1) << 6, nh = (wave >> 1) << 6;

    #pragma unroll
    for (int j = 0; j < 4; j++) {
        int col = n0 + nh + (j << 4) + cl;
        float bv = bias[col];
        #pragma unroll
        for (int i = 0; i < 4; i++) {
            int row0 = m0 + mh + (i << 4) + (qd << 2);
            #pragma unroll
            for (int r = 0; r < 4; r++) {
                int row = row0 + r;
                if (row < M) {
                    float v = acc[i][j][r] + bv;
                    if (R) v += R[(size_t)row * N + col];
                    if (act) v = 0.5f * v * (1.0f + erff(v * 0.70710678118654752f));
                    if (C)  C[(size_t)row * N + col] = v;
                    if (Cb) Cb[(size_t)row * N + col] = f2b(v);
                }
            }
        }
    }
}

// ---------------------------------------------------------------- QKV GEMM: writes Q,K row-major + V transposed
__global__ __launch_bounds__(256) void gemm_qkv(const unsigned short* __restrict__ A,
                                                const unsigned short* __restrict__ W,
                                                const float* __restrict__ bias,
                                                unsigned short* __restrict__ Q,
                                                unsigned short* __restrict__ Kd,
                                                unsigned short* __restrict__ vT,
                                                int M, int N, int K) {
    __shared__ __align__(16) unsigned short As[3 * 4096];
    __shared__ __align__(16) unsigned short Ws[3 * 4096];
    int bx, by, bz;
    swz_bxyz(bx, by, bz);
    int m0 = by << 7, n0 = bx << 7;

    ffrag acc[4][4] = {};
    gemm_core(A, W, M, K, m0, n0, 0, K >> 5, As, Ws, acc);

    int tid = threadIdx.x;
    int wave = tid >> 6, lane = tid & 63;
    int cl = lane & 15, qd = lane >> 4;
    int mh = (wave & 1) << 6, nh = (wave >> 1) << 6;

    int ncb = n0 + nh;                        // 64-aligned col base for this wave
    if (ncb < 1536) {
        unsigned short* dst = (ncb < 768) ? Q : Kd;
        int cb = (ncb < 768) ? 0 : 768;
        #pragma unroll
        for (int j = 0; j < 4; j++) {
            int col = ncb + (j << 4) + cl;
            float bv = bias[col];
            #pragma unroll
            for (int i = 0; i < 4; i++) {
                int row0 = m0 + mh + (i << 4) + (qd << 2);
                #pragma unroll
                for (int r = 0; r < 4; r++) {
                    int row = row0 + r;
                    if (row < M)
                        dst[(size_t)row * EE + col - cb] = f2b(acc[i][j][r] + bv);
                }
            }
        }
    } else {
        int hh = (ncb - 1536) >> 6;           // uniform per wave
        #pragma unroll
        for (int i = 0; i < 4; i++) {
            int row0 = m0 + mh + (i << 4) + (qd << 2);
            #pragma unroll
            for (int r = 0; r < 4; r++) {
                int row = row0 + r;
                if (row < M) {
                    int b = row / TT;
                    int t = row - b * TT;
                    size_t vbase = ((size_t)(b * NHEAD + hh) * 64) * TTP + t;
                    #pragma unroll
                    for (int j = 0; j < 4; j++) {
                        int col = ncb + (j << 4) + cl;
                        vT[vbase + (size_t)((j << 4) + cl) * TTP] =
                            f2b(acc[i][j][r] + bias[col]);
                    }
                }
            }
        }
    }
}

// ---------------------------------------------------------------- split-K bf16 MFMA GEMM (atomic fp32)
__global__ __launch_bounds__(256) void gemm_bf16_sk(const unsigned short* __restrict__ A,
                                                    const unsigned short* __restrict__ W,
                                                    const float* __restrict__ bias,
                                                    float* C,
                                                    int M, int N, int K, int KC) {
    __shared__ __align__(16) unsigned short As[3 * 4096];
    __shared__ __align__(16) unsigned short Ws[3 * 4096];
    int bx, by, bz;
    swz_bxyz(bx, by, bz);
    int m0 = by << 7, n0 = bx << 7;
    int z = bz;
    int kbeg = z * KC;
    int kc2 = (kbeg + KC > K) ? (K - kbeg) : KC;

    ffrag acc[4][4] = {};
    gemm_core(A, W, M, K, m0, n0, kbeg, kc2 >> 5, As, Ws, acc);

    int tid = threadIdx.x;
    int wave = tid >> 6, lane = tid & 63;
    int cl = lane & 15, qd = lane >> 4;
    int mh = (wave & 1) << 6, nh = (wave >> 1) << 6;

    #pragma unroll
    for (int j = 0; j < 4; j++) {
        int col = n0 + nh + (j << 4) + cl;
        float bv = (z == 0) ? bias[col] : 0.0f;
        #pragma unroll
        for (int i = 0; i < 4; i++) {
            int row0 = m0 + mh + (i << 4) + (qd << 2);
            #pragma unroll
            for (int r = 0; r < 4; r++) {
                int row = row0 + r;
                if (row < M)
                    unsafeAtomicAdd(&C[(size_t)row * N + col], acc[i][j][r] + bv);
            }
        }
    }
}

// ---------------------------------------------------------------- MFMA flash attention v5
// Changes vs v4: mask bitmask table (no per-tile int mask math), l via ones-column
// MFMA fragment (no sum shfl-reduce), raw v_exp/v_rcp, P-store block rotation
// (bank-conflict-free b16 writes), reg-prefetch of next K/V tile, XCD swizzle.
#define LP 72
#define SCL2 0.18033688011112042f   // 0.125 * log2(e)
__global__ __launch_bounds__(256) void attn_kernel(const unsigned short* __restrict__ Qg,
                                                   const unsigned short* __restrict__ Kg,
                                                   const unsigned short* __restrict__ vT,
                                                   const unsigned long long* __restrict__ mtab,
                                                   unsigned short* __restrict__ O) {
    __shared__ unsigned short Ks[64 * LP];     // [k'][d]
    __shared__ unsigned short Vt[80 * LP];     // [d][k']; rows 64..79 = ones row + zeros
    __shared__ unsigned short Pb[64 * LP];     // [q_local][k' block-rotated]
    int tid = threadIdx.x;
    int wave = tid >> 6, lane = tid & 63;
    int cl = lane & 15, qd = lane >> 4;
    int bx, by, bz;
    swz_bxyz(bx, by, bz);                      // group all 13 q-tiles of a head on one XCD
    int bh = by;
    int b = bh / NHEAD, hh = bh % NHEAD;
    int q0 = bx * 64;
    int qw = q0 + wave * 16;

    // ones row (d=64) + zero rows (65..79) for the l-accumulating fragment t=4
    for (int i = tid; i < 16 * LP; i += 256)
        Vt[64 * LP + i] = (i < LP) ? (unsigned short)0x3F80 : (unsigned short)0;

    int qrow = qw + cl;
    if (qrow > TT - 1) qrow = TT - 1;
    const unsigned short* qb = Qg + (size_t)(b * TT + qrow) * EE + hh * 64;
    bfrag qf0 = *(const bfrag*)(qb + (qd << 3));
    bfrag qf1 = *(const bfrag*)(qb + 32 + (qd << 3));

    ffrag o_acc[5] = {};                       // [0..3]=O, [4]=l (ones column)
    float m_run[4];
    int qg_[4], qm_[4];
    #pragma unroll
    for (int r = 0; r < 4; r++) {
        qg_[r] = qw + (qd << 2) + r;
        qm_[r] = qg_[r] > TT - 1 ? TT - 1 : qg_[r];
        m_run[r] = -1e30f;
    }

    const unsigned short* kbase = Kg + (size_t)b * TT * EE + hh * 64;
    const unsigned short* vbase = vT + (size_t)(b * NHEAD + hh) * 64 * TTP;
    int srow = tid >> 3;            // 0..31
    int scol = (tid & 7) << 3;      // 0..56
    int r0 = srow, r1 = 32 + srow;
    const unsigned short* vp0 = vbase + (size_t)r0 * TTP + scol;
    const unsigned short* vp1 = vbase + (size_t)r1 * TTP + scol;

    // prefetch tile 0 into regs
    bfrag kreg0 = *(const bfrag*)(kbase + (size_t)r0 * EE + scol);
    bfrag kreg1 = *(const bfrag*)(kbase + (size_t)r1 * EE + scol);
    bfrag vreg0 = *(const bfrag*)vp0;
    bfrag vreg1 = *(const bfrag*)vp1;

    // P read addresses (undo the per-row block rotation)
    int rot = (cl >> 2) & 3;
    int pread0 = (wave * 16 + cl) * LP + ((((qd >> 1)    ) ^ rot) << 4) + ((qd & 1) << 3);
    int pread1 = (wave * 16 + cl) * LP + (((2 + (qd >> 1)) ^ rot) << 4) + ((qd & 1) << 3);

    for (int k0 = 0; k0 < 832; k0 += 64) {
        __syncthreads();           // all reads of previous tile done
        *(bfrag*)&Ks[r0 * LP + scol] = kreg0;
        *(bfrag*)&Ks[r1 * LP + scol] = kreg1;
        *(bfrag*)&Vt[r0 * LP + scol] = vreg0;
        *(bfrag*)&Vt[r1 * LP + scol] = vreg1;

        // mask bits for this tile (4 x 8B loads, L1/L2-hot 82 KB table)
        int tix = k0 >> 6;
        unsigned mlo[4], mhi[4];
        #pragma unroll
        for (int r = 0; r < 4; r++) {
            unsigned long long mb = mtab[qm_[r] * 13 + tix];
            mlo[r] = (unsigned)mb;
            mhi[r] = (unsigned)(mb >> 32);
        }
        __syncthreads();           // tile staged

        // prefetch next tile into regs (overlaps compute below)
        if (k0 + 64 < 832) {
            int kn = k0 + 64;
            int t0 = kn + r0; if (t0 > TT - 1) t0 = TT - 1;
            int t1 = kn + r1; if (t1 > TT - 1) t1 = TT - 1;
            kreg0 = *(const bfrag*)(kbase + (size_t)t0 * EE + scol);
            kreg1 = *(const bfrag*)(kbase + (size_t)t1 * EE + scol);
            vreg0 = *(const bfrag*)(vp0 + kn);
            vreg1 = *(const bfrag*)(vp1 + kn);
        }

        // S = Q K^T
        ffrag sv[4];
        #pragma unroll
        for (int j = 0; j < 4; j++) {
            bfrag kf0 = *(const bfrag*)&Ks[(j * 16 + cl) * LP + (qd << 3)];
            bfrag kf1 = *(const bfrag*)&Ks[(j * 16 + cl) * LP + 32 + (qd << 3)];
            ffrag z = {0.f, 0.f, 0.f, 0.f};
            z = __builtin_amdgcn_mfma_f32_16x16x32_bf16(qf0, kf0, z, 0, 0, 0);
            z = __builtin_amdgcn_mfma_f32_16x16x32_bf16(qf1, kf1, z, 0, 0, 0);
            sv[j] = z;
        }

        // mask via table bits
        #pragma unroll
        for (int j = 0; j < 4; j++) {
            #pragma unroll
            for (int r = 0; r < 4; r++) {
                unsigned sel = (j < 2) ? mlo[r] : mhi[r];
                if ((sel >> (((j & 1) << 4) + cl)) & 1) sv[j][r] = -3.0e38f;
            }
        }

        // online softmax; l accumulates in o_acc[4] via the ones column
        #pragma unroll
        for (int r = 0; r < 4; r++) {
            float mx = fmaxf(fmaxf(sv[0][r], sv[1][r]), fmaxf(sv[2][r], sv[3][r]));
            mx = fmaxf(mx, __shfl_xor(mx, 1, 64));
            mx = fmaxf(mx, __shfl_xor(mx, 2, 64));
            mx = fmaxf(mx, __shfl_xor(mx, 4, 64));
            mx = fmaxf(mx, __shfl_xor(mx, 8, 64));
            float m_new = fmaxf(m_run[r], mx);
            float alpha = fexp2((m_run[r] - m_new) * SCL2);
            float p0 = fexp2((sv[0][r] - m_new) * SCL2);
            float p1 = fexp2((sv[1][r] - m_new) * SCL2);
            float p2 = fexp2((sv[2][r] - m_new) * SCL2);
            float p3 = fexp2((sv[3][r] - m_new) * SCL2);
            m_run[r] = m_new;
            #pragma unroll
            for (int t = 0; t < 5; t++) o_acc[t][r] *= alpha;
            int prow = (wave * 16 + (qd << 2) + r) * LP;
            Pb[prow + ((0 ^ qd) << 4) + cl] = f2b(p0);   // block-rotated store:
            Pb[prow + ((1 ^ qd) << 4) + cl] = f2b(p1);   // disjoint bank windows
            Pb[prow + ((2 ^ qd) << 4) + cl] = f2b(p2);   // per qd group
            Pb[prow + ((3 ^ qd) << 4) + cl] = f2b(p3);
        }
        // Pb rows are wave-private: drain this wave's LDS writes only
        asm volatile("s_waitcnt lgkmcnt(0)" ::: "memory");

        // O += P @ V  (t=4 accumulates l against the ones row)
        bfrag pf0 = *(const bfrag*)&Pb[pread0];
        bfrag pf1 = *(const bfrag*)&Pb[pread1];
        #pragma unroll
        for (int t = 0; t < 5; t++) {
            bfrag vf0 = *(const bfrag*)&Vt[(t * 16 + cl) * LP + (qd << 3)];
            bfrag vf1 = *(const bfrag*)&Vt[(t * 16 + cl) * LP + 32 + (qd << 3)];
            o_acc[t] = __builtin_amdgcn_mfma_f32_16x16x32_bf16(pf0, vf0, o_acc[t], 0, 0, 0);
            o_acc[t] = __builtin_amdgcn_mfma_f32_16x16x32_bf16(pf1, vf1, o_acc[t], 0, 0, 0);
        }
    }

    #pragma unroll
    for (int r = 0; r < 4; r++) {
        // l lives in column 0 of fragment 4 -> lanes qd*16; broadcast within group
        float l = __shfl(o_acc[4][r], lane & 48, 64);
        float inv = frcp(fmaxf(l, 1e-30f));
        if (qg_[r] < TT) {
            #pragma unroll
            for (int t = 0; t < 4; t++)
                O[(size_t)(b * TT + qg_[r]) * EE + hh * 64 + t * 16 + cl] =
                    f2b(o_acc[t][r] * inv);
        }
    }
}

// ---------------------------------------------------------------- head
__global__ __launch_bounds__(256) void head_kernel(const float* __restrict__ Y,
                                                   const float* __restrict__ hw,
                                                   const float* __restrict__ hb,
                                                   const float* __restrict__ mean_,
                                                   const float* __restrict__ std_,
                                                   float* __restrict__ out) {
    __shared__ float sb[4];
    int row = blockIdx.x;
    int tid = threadIdx.x;
    const float* y = Y + (size_t)row * EE;
    float v = y[tid] * hw[tid] + y[tid + 256] * hw[tid + 256] + y[tid + 512] * hw[tid + 512];
    v = block_reduce_sum256(v, sb);
    if (tid == 0) {
        float logit = v + hb[0];
        float z = logit * std_[0] + mean_[0];
        float f = expf(z * 2.302585092994046f) - 1e-8f;
        f = fminf(fmaxf(f, 1e-15f), 1.0f);
        out[4 + row] = f;
    }
}

__global__ __launch_bounds__(256) void flux_sum_kernel(float* __restrict__ out) {
    __shared__ float sb[4];
    int b = blockIdx.x;
    int tid = threadIdx.x;
    const float* pf = out + 4 + (size_t)b * TT;
    float v = pf[tid] + pf[tid + 256] + pf[tid + 512];
    if (tid < TT - 768) v += pf[tid + 768];
    v = block_reduce_sum256(v, sb);
    if (tid == 0) out[b] = fmaxf(v, 1e-15f);
}

// ---------------------------------------------------------------- host
extern "C" void kernel_launch(void* const* d_in, const int* in_sizes, int n_in,
                              void* d_out, int out_size, void* d_ws, size_t ws_size,
                              hipStream_t stream) {
    const float* x        = (const float*)d_in[0];
    const float* sxr_mean = (const float*)d_in[1];
    const float* sxr_std  = (const float*)d_in[2];
    const float* input_w  = (const float*)d_in[3];
    const float* input_b  = (const float*)d_in[4];
    const float* pos_emb  = (const float*)d_in[5];
    const float* ln1_w    = (const float*)d_in[6];
    const float* ln1_b    = (const float*)d_in[7];
    const float* in_w     = (const float*)d_in[8];
    const float* in_b     = (const float*)d_in[9];
    const float* out_w    = (const float*)d_in[10];
    const float* out_b    = (const float*)d_in[11];
    const float* ln2_w    = (const float*)d_in[12];
    const float* ln2_b    = (const float*)d_in[13];
    const float* w1       = (const float*)d_in[14];
    const float* b1       = (const float*)d_in[15];
    const float* w2       = (const float*)d_in[16];
    const float* b2       = (const float*)d_in[17];
    const float* head_ln_w = (const float*)d_in[18];
    const float* head_ln_b = (const float*)d_in[19];
    const float* head_w   = (const float*)d_in[20];
    const float* head_b   = (const float*)d_in[21];
    float* out = (float*)d_out;

    const size_t NROW = (size_t)BB * TT;               // 3136
    const size_t NE   = NROW * EE;

    float* h   = (float*)d_ws;                         // [3136,768] f32
    float* y32 = h + NE;                               // [3136,768] f32 (head only)
    unsigned short* q_b   = (unsigned short*)(y32 + NE);   // [3136,768] bf16
    unsigned short* k_b   = q_b + NE;                      // [3136,768] bf16
    unsigned short* vT_b  = k_b + NE;                      // [48*64, 832] bf16
    unsigned short* y_b   = vT_b + (size_t)BB * NHEAD * 64 * TTP;
    unsigned short* o_b   = y_b + NE;
    unsigned short* mlp_b = o_b + NE;                  // [3136,3072] bf16
    unsigned short* wq_b  = mlp_b + NROW * HDIM;
    unsigned short* wo_b  = wq_b + (size_t)3 * EE * EE;
    unsigned short* w1_b  = wo_b + (size_t)EE * EE;
    unsigned short* w2_b  = w1_b + (size_t)HDIM * EE;
    unsigned long long* mtab = (unsigned long long*)(w2_b + (size_t)EE * HDIM);  // [784*13] u64

    const int tot = BB * TT * EE;
    const int GY = (int)((NROW + 127) / 128);          // 25

    patchify_kernel<<<(tot + 255) / 256, 256, 0, stream>>>(x, mlp_b);
    cast_kernel<<<(EE * EE / 4 + 255) / 256, 256, 0, stream>>>(input_w, wo_b, EE * EE / 4);
    posfill_kernel<<<(tot + 255) / 256, 256, 0, stream>>>(h, pos_emb);
    mask_build_kernel<<<(TT * 13 + 255) / 256, 256, 0, stream>>>(mtab);
    gemm_bf16_sk<<<dim3(EE / 128, GY, 4), 256, 0, stream>>>(
        mlp_b, wo_b, input_b, h, (int)NROW, EE, EE, 192);

    for (int l = 0; l < NLAYER; l++) {
        fused_cast_kernel<<<6912, 256, 0, stream>>>(
            in_w + (size_t)l * 3 * EE * EE, out_w + (size_t)l * EE * EE,
            w1 + (size_t)l * HDIM * EE, w2 + (size_t)l * EE * HDIM,
            wq_b, wo_b, w1_b, w2_b);

        ln_kernel<<<(int)NROW, 256, 0, stream>>>(h, ln1_w + l * EE, ln1_b + l * EE, y_b, nullptr);
        gemm_qkv<<<dim3(3 * EE / 128, GY), 256, 0, stream>>>(
            y_b, wq_b, in_b + (size_t)l * 3 * EE, q_b, k_b, vT_b,
            (int)NROW, 3 * EE, EE);
        attn_kernel<<<dim3(13, BB * NHEAD), 256, 0, stream>>>(q_b, k_b, vT_b, mtab, o_b);
        gemm_bf16_sk<<<dim3(EE / 128, GY, 4), 256, 0, stream>>>(
            o_b, wo_b, out_b + (size_t)l * EE, h, (int)NROW, EE, EE, 192);
        ln_kernel<<<(int)NROW, 256, 0, stream>>>(h, ln2_w + l * EE, ln2_b + l * EE, y_b, nullptr);
        gemm_bf16<<<dim3(HDIM / 128, GY), 256, 0, stream>>>(
            y_b, w1_b, b1 + (size_t)l * HDIM, nullptr, nullptr, mlp_b,
            (int)NROW, HDIM, EE, 1);
        gemm_bf16_sk<<<dim3(EE / 128, GY, 4), 256, 0, stream>>>(
            mlp_b, w2_b, b2 + (size_t)l * EE, h, (int)NROW, EE, HDIM, 768);
    }

    ln_kernel<<<(int)NROW, 256, 0, stream>>>(h, head_ln_w, head_ln_b, y_b, y32);
    head_kernel<<<(int)NROW, 256, 0, stream>>>(y32, head_w, head_b, sxr_mean, sxr_std, out);
    flux_sum_kernel<<<BB, 256, 0, stream>>>(out);
}

// Round 4
// 1418.192 us; speedup vs baseline: 1.4346x; 1.1164x over previous
//
#include <hip/hip_runtime.h>
#include <math.h>

#define BB 4
#define TT 784
#define GG 28
#define EE 768
#define HDIM 3072
#define NHEAD 12
#define NLAYER 6
#define TTP 832           // padded token stride for vT
#define PSL (3136 * 768)  // partial slice length (f32 elems)

typedef short bfrag __attribute__((ext_vector_type(8)));   // 8 bf16 = 4 VGPRs
typedef float ffrag __attribute__((ext_vector_type(4)));   // 4 fp32 acc

__device__ __forceinline__ unsigned short f2b(float f) {
    union { float f; unsigned u; } v; v.f = f;
    unsigned r = v.u + 0x7FFF + ((v.u >> 16) & 1);         // RNE
    return (unsigned short)(r >> 16);
}

__device__ __forceinline__ float fexp2(float x) {          // raw v_exp_f32 (2^x)
    float r; asm("v_exp_f32 %0, %1" : "=v"(r) : "v"(x)); return r;
}
__device__ __forceinline__ float frcp(float x) {           // raw v_rcp_f32
    float r; asm("v_rcp_f32 %0, %1" : "=v"(r) : "v"(x)); return r;
}

#define GLOAD_LDS16(g, l)                                                          \
    __builtin_amdgcn_global_load_lds(                                              \
        (const __attribute__((address_space(1))) void*)(g),                        \
        (__attribute__((address_space(3))) void*)(l), 16, 0, 0)

// bijective XCD swizzle (m204): consecutive tiles land on the same XCD's L2
__device__ __forceinline__ void swz_bxyz(int& bx, int& by, int& bz) {
    int gx = gridDim.x, gy = gridDim.y, gz = gridDim.z;
    int nwg = gx * gy * gz;
    int orig = blockIdx.x + gx * (blockIdx.y + gy * blockIdx.z);
    int q = nwg >> 3, r = nwg & 7;
    int xc = orig & 7, li = orig >> 3;
    int wg = (xc < r ? xc * (q + 1) : r * (q + 1) + (xc - r) * q) + li;
    bx = wg % gx;
    int t = wg / gx;
    by = t % gy;
    bz = t / gy;
}

// ---------------------------------------------------------------- reductions
__device__ __forceinline__ float block_reduce_sum256(float v, volatile float* sb) {
    #pragma unroll
    for (int m = 1; m < 64; m <<= 1) v += __shfl_xor(v, m, 64);
    int wave = threadIdx.x >> 6;
    if ((threadIdx.x & 63) == 0) sb[wave] = v;
    __syncthreads();
    return sb[0] + sb[1] + sb[2] + sb[3];
}

__device__ __forceinline__ float block_reduce_sum192(float v, volatile float* sb) {
    #pragma unroll
    for (int m = 1; m < 64; m <<= 1) v += __shfl_xor(v, m, 64);
    int wave = threadIdx.x >> 6;
    if ((threadIdx.x & 63) == 0) sb[wave] = v;
    __syncthreads();
    return sb[0] + sb[1] + sb[2];
}

// ---------------------------------------------------------------- fp32 -> bf16 cast
__global__ __launch_bounds__(256) void cast_kernel(const float* __restrict__ s,
                                                   unsigned short* __restrict__ d, int n4) {
    int i = blockIdx.x * 256 + threadIdx.x;
    if (i >= n4) return;
    float4 v = ((const float4*)s)[i];
    ushort4 o;
    o.x = f2b(v.x); o.y = f2b(v.y); o.z = f2b(v.z); o.w = f2b(v.w);
    ((ushort4*)d)[i] = o;
}

// ---------------------------------------------------------------- fused per-layer weight cast
__global__ __launch_bounds__(256) void fused_cast_kernel(const float* __restrict__ iw,
                                                         const float* __restrict__ ow,
                                                         const float* __restrict__ W1,
                                                         const float* __restrict__ W2,
                                                         unsigned short* __restrict__ dq,
                                                         unsigned short* __restrict__ doo,
                                                         unsigned short* __restrict__ d1,
                                                         unsigned short* __restrict__ d2) {
    int i = blockIdx.x * 256 + threadIdx.x;
    const float* s; unsigned short* d; int k;
    if (i < 442368)            { s = iw;  d = dq;  k = i; }
    else if (i < 589824)       { s = ow;  d = doo; k = i - 442368; }
    else if (i < 1179648)      { s = W1;  d = d1;  k = i - 589824; }
    else if (i < 1769472)      { s = W2;  d = d2;  k = i - 1179648; }
    else return;
    float4 v = ((const float4*)s)[k];
    ushort4 o;
    o.x = f2b(v.x); o.y = f2b(v.y); o.z = f2b(v.z); o.w = f2b(v.w);
    ((ushort4*)d)[k] = o;
}

// ---------------------------------------------------------------- patchify -> bf16
__global__ __launch_bounds__(256) void patchify_kernel(const float* __restrict__ x,
                                                       unsigned short* __restrict__ P) {
    int idx = blockIdx.x * blockDim.x + threadIdx.x;
    const int total = BB * TT * EE;
    if (idx >= total) return;
    int k = idx % EE;
    int t = (idx / EE) % TT;
    int b = idx / (EE * TT);
    int c = k >> 8;
    int rem = k & 255;
    int p1 = rem >> 4;
    int p2 = rem & 15;
    int g1 = t / GG, g2 = t % GG;
    int hh = g1 * 16 + p1, ww = g2 * 16 + p2;
    P[idx] = f2b(x[((b * 448 + hh) * 448 + ww) * 3 + c]);
}

// ---------------------------------------------------------------- pos prefill
__global__ __launch_bounds__(256) void posfill_kernel(float* __restrict__ h,
                                                      const float* __restrict__ pos) {
    int idx = blockIdx.x * blockDim.x + threadIdx.x;
    const int total = BB * TT * EE;
    if (idx >= total) return;
    h[idx] = pos[idx % (TT * EE)];
}

// ---------------------------------------------------------------- local-window mask bit table
__global__ __launch_bounds__(256) void mask_build_kernel(unsigned long long* __restrict__ mt) {
    int idx = blockIdx.x * 256 + threadIdx.x;
    if (idx >= TT * 13) return;
    int row = idx / 13, t = idx % 13;
    int qr = row / GG, qc = row % GG;
    unsigned long long bits = 0;
    for (int i = 0; i < 64; i++) {
        int k = t * 64 + i;
        bool m;
        if (k >= TT) m = true;
        else {
            int kr2 = k / GG, kc2 = k % GG;
            m = (abs(qr - kr2) <= 4) && (abs(qc - kc2) <= 4);
        }
        if (m) bits |= (1ull << i);
    }
    mt[idx] = bits;
}

// ---------------------------------------------------------------- fused partial-reduce + layernorm
// h <- h + P0+P1+P2+P3 (written back); y = LN(h)*g + b -> bf16 (+ f32 for head)
__global__ __launch_bounds__(192) void ln_red_kernel(float* __restrict__ H,
                                                     const float* __restrict__ P,
                                                     const float* __restrict__ g,
                                                     const float* __restrict__ bt,
                                                     unsigned short* __restrict__ Yb,
                                                     float* __restrict__ Yf) {
    __shared__ float sb1[3];
    __shared__ float sb2[3];
    int row = blockIdx.x, tid = threadIdx.x;
    size_t base = (size_t)row * EE + tid * 4;
    float4 hv = *(float4*)(H + base);
    float4 p0 = *(const float4*)(P + base);
    float4 p1 = *(const float4*)(P + (size_t)PSL + base);
    float4 p2 = *(const float4*)(P + 2 * (size_t)PSL + base);
    float4 p3 = *(const float4*)(P + 3 * (size_t)PSL + base);
    hv.x += (p0.x + p1.x) + (p2.x + p3.x);
    hv.y += (p0.y + p1.y) + (p2.y + p3.y);
    hv.z += (p0.z + p1.z) + (p2.z + p3.z);
    hv.w += (p0.w + p1.w) + (p2.w + p3.w);
    *(float4*)(H + base) = hv;
    float s = block_reduce_sum192((hv.x + hv.y) + (hv.z + hv.w), sb1);
    float mean = s * (1.0f / 768.0f);
    float dx = hv.x - mean, dy = hv.y - mean, dz = hv.z - mean, dw = hv.w - mean;
    __syncthreads();
    float ss = block_reduce_sum192((dx * dx + dy * dy) + (dz * dz + dw * dw), sb2);
    float rstd = rsqrtf(ss * (1.0f / 768.0f) + 1e-5f);
    float4 gv = *(const float4*)(g + tid * 4);
    float4 bv = *(const float4*)(bt + tid * 4);
    float y0 = dx * rstd * gv.x + bv.x;
    float y1 = dy * rstd * gv.y + bv.y;
    float y2 = dz * rstd * gv.z + bv.z;
    float y3 = dw * rstd * gv.w + bv.w;
    ushort4 o;
    o.x = f2b(y0); o.y = f2b(y1); o.z = f2b(y2); o.w = f2b(y3);
    *(ushort4*)(Yb + base) = o;
    if (Yf) {
        float4 yf; yf.x = y0; yf.y = y1; yf.z = y2; yf.w = y3;
        *(float4*)(Yf + base) = yf;
    }
}

// ---------------------------------------------------------------- pipelined MFMA core v2
// BK=32, TRIPLE-buffered LDS (48 KB -> 3 blocks/CU), prefetch depth 2,
// counted vmcnt; s_setprio(1) around MFMA cluster (T5 — blocks at different
// phases on one CU give the scheduler role diversity to arbitrate).
__device__ __forceinline__ void gemm_core(const unsigned short* __restrict__ A,
                                          const unsigned short* __restrict__ W,
                                          int M, int K, int m0, int n0,
                                          int kbeg, int nk,
                                          unsigned short* As,   // [3*4096]
                                          unsigned short* Ws,   // [3*4096]
                                          ffrag (&acc)[4][4]) {
    int tid = threadIdx.x;
    int wave = tid >> 6, lane = tid & 63;
    int cl = lane & 15, qd = lane >> 4;
    int sr  = lane >> 2;                 // staged row within 16-row group (0..15)
    int sbk = lane & 3;                  // 16B-block index within 64B row
    int ssc = (sbk ^ (sr & 3)) << 3;     // pre-swizzled source col (shorts)
    int mh = (wave & 1) << 6, nh = (wave >> 1) << 6;

    const unsigned short* Asrc0;
    const unsigned short* Asrc1;
    const unsigned short* Wsrc0;
    const unsigned short* Wsrc1;
    {
        int ar0 = m0 + (wave << 5) + sr;       if (ar0 > M - 1) ar0 = M - 1;
        int ar1 = m0 + (wave << 5) + 16 + sr;  if (ar1 > M - 1) ar1 = M - 1;
        Asrc0 = A + (size_t)ar0 * K + kbeg + ssc;
        Asrc1 = A + (size_t)ar1 * K + kbeg + ssc;
        int wr0 = n0 + (wave << 5) + sr;
        int wr1 = n0 + (wave << 5) + 16 + sr;
        Wsrc0 = W + (size_t)wr0 * K + kbeg + ssc;
        Wsrc1 = W + (size_t)wr1 * K + kbeg + ssc;
    }
    int dof0 = (wave << 10);            // wave's 32-row slice = 1024 shorts
    int dof1 = (wave << 10) + 512;
    int fo = (qd ^ (cl & 3)) << 3;      // swizzled read offset (shorts)

#define STAGE32(sa, sw, kk) do {                         \
        GLOAD_LDS16(Asrc0 + (kk), (sa) + dof0);          \
        GLOAD_LDS16(Asrc1 + (kk), (sa) + dof1);          \
        GLOAD_LDS16(Wsrc0 + (kk), (sw) + dof0);          \
        GLOAD_LDS16(Wsrc1 + (kk), (sw) + dof1);          \
    } while (0)

    unsigned short *a0 = As, *a1 = As + 4096, *a2 = As + 8192;
    unsigned short *w0 = Ws, *w1 = Ws + 4096, *w2 = Ws + 8192;

    STAGE32(a0, w0, 0);
    if (nk > 1) STAGE32(a1, w1, 32);

    for (int t = 0; t < nk; ++t) {
        if (t + 2 < nk) {
            STAGE32(a2, w2, (t + 2) << 5);
            asm volatile("s_waitcnt vmcnt(8)" ::: "memory");   // tile t done; t+1,t+2 in flight
        } else if (t + 1 < nk) {
            asm volatile("s_waitcnt vmcnt(4)" ::: "memory");   // tile t done; t+1 in flight
        } else {
            asm volatile("s_waitcnt vmcnt(0)" ::: "memory");
        }
        __builtin_amdgcn_s_barrier();
        __builtin_amdgcn_sched_barrier(0);

        bfrag af[4], bf[4];
        #pragma unroll
        for (int i = 0; i < 4; i++)
            af[i] = *(const bfrag*)&a0[((mh + (i << 4) + cl) << 5) + fo];
        #pragma unroll
        for (int j = 0; j < 4; j++)
            bf[j] = *(const bfrag*)&w0[((nh + (j << 4) + cl) << 5) + fo];
        __builtin_amdgcn_s_setprio(1);
        #pragma unroll
        for (int i = 0; i < 4; i++)
            #pragma unroll
            for (int j = 0; j < 4; j++)
                acc[i][j] = __builtin_amdgcn_mfma_f32_16x16x32_bf16(af[i], bf[j], acc[i][j], 0, 0, 0);
        __builtin_amdgcn_s_setprio(0);

        __builtin_amdgcn_s_barrier();   // all reads of a0/w0 done before restage
        unsigned short* tp;
        tp = a0; a0 = a1; a1 = a2; a2 = tp;
        tp = w0; w0 = w1; w1 = w2; w2 = tp;
    }
#undef STAGE32
}

// ---------------------------------------------------------------- bf16 MFMA GEMM (generic)
__global__ __launch_bounds__(256) void gemm_bf16(const unsigned short* __restrict__ A,
                                                 const unsigned short* __restrict__ W,
                                                 const float* __restrict__ bias,
                                                 const float* R, float* C,
                                                 unsigned short* Cb,
                                                 int M, int N, int K, int act) {
    __shared__ __align__(16) unsigned short As[3 * 4096];
    __shared__ __align__(16) unsigned short Ws[3 * 4096];
    int bx, by, bz;
    swz_bxyz(bx, by, bz);
    int m0 = by << 7, n0 = bx << 7;

    ffrag acc[4][4] = {};
    gemm_core(A, W, M, K, m0, n0, 0, K >> 5, As, Ws, acc);

    int tid = threadIdx.x;
    int wave = tid >> 6, lane = tid & 63;
    int cl = lane & 15, qd = lane >> 4;
    int mh = (wave & 1) << 6, nh = (wave >> 1) << 6;

    #pragma unroll
    for (int j = 0; j < 4; j++) {
        int col = n0 + nh + (j << 4) + cl;
        float bv = bias[col];
        #pragma unroll
        for (int i = 0; i < 4; i++) {
            int row0 = m0 + mh + (i << 4) + (qd << 2);
            #pragma unroll
            for (int r = 0; r < 4; r++) {
                int row = row0 + r;
                if (row < M) {
                    float v = acc[i][j][r] + bv;
                    if (R) v += R[(size_t)row * N + col];
                    if (act) v = 0.5f * v * (1.0f + erff(v * 0.70710678118654752f));
                    if (C)  C[(size_t)row * N + col] = v;
                    if (Cb) Cb[(size_t)row * N + col] = f2b(v);
                }
            }
        }
    }
}

// ---------------------------------------------------------------- QKV GEMM: writes Q,K row-major + V transposed
__global__ __launch_bounds__(256) void gemm_qkv(const unsigned short* __restrict__ A,
                                                const unsigned short* __restrict__ W,
                                                const float* __restrict__ bias,
                                                unsigned short* __restrict__ Q,
                                                unsigned short* __restrict__ Kd,
                                                unsigned short* __restrict__ vT,
                                                int M, int N, int K) {
    __shared__ __align__(16) unsigned short As[3 * 4096];
    __shared__ __align__(16) unsigned short Ws[3 * 4096];
    int bx, by, bz;
    swz_bxyz(bx, by, bz);
    int m0 = by << 7, n0 = bx << 7;

    ffrag acc[4][4] = {};
    gemm_core(A, W, M, K, m0, n0, 0, K >> 5, As, Ws, acc);

    int tid = threadIdx.x;
    int wave = tid >> 6, lane = tid & 63;
    int cl = lane & 15, qd = lane >> 4;
    int mh = (wave & 1) << 6, nh = (wave >> 1) << 6;

    int ncb = n0 + nh;                        // 64-aligned col base for this wave
    if (ncb < 1536) {
        unsigned short* dst = (ncb < 768) ? Q : Kd;
        int cb = (ncb < 768) ? 0 : 768;
        #pragma unroll
        for (int j = 0; j < 4; j++) {
            int col = ncb + (j << 4) + cl;
            float bv = bias[col];
            #pragma unroll
            for (int i = 0; i < 4; i++) {
                int row0 = m0 + mh + (i << 4) + (qd << 2);
                #pragma unroll
                for (int r = 0; r < 4; r++) {
                    int row = row0 + r;
                    if (row < M)
                        dst[(size_t)row * EE + col - cb] = f2b(acc[i][j][r] + bv);
                }
            }
        }
    } else {
        int hh = (ncb - 1536) >> 6;           // uniform per wave
        #pragma unroll
        for (int i = 0; i < 4; i++) {
            int row0 = m0 + mh + (i << 4) + (qd << 2);
            #pragma unroll
            for (int r = 0; r < 4; r++) {
                int row = row0 + r;
                if (row < M) {
                    int b = row / TT;
                    int t = row - b * TT;
                    size_t vbase = ((size_t)(b * NHEAD + hh) * 64) * TTP + t;
                    #pragma unroll
                    for (int j = 0; j < 4; j++) {
                        int col = ncb + (j << 4) + cl;
                        vT[vbase + (size_t)((j << 4) + cl) * TTP] =
                            f2b(acc[i][j][r] + bias[col]);
                    }
                }
            }
        }
    }
}

// ---------------------------------------------------------------- split-K bf16 MFMA GEMM (partial slices, no atomics)
__global__ __launch_bounds__(256) void gemm_bf16_pk(const unsigned short* __restrict__ A,
                                                    const unsigned short* __restrict__ W,
                                                    const float* __restrict__ bias,
                                                    float* __restrict__ Pp,
                                                    int M, int N, int K, int KC) {
    __shared__ __align__(16) unsigned short As[3 * 4096];
    __shared__ __align__(16) unsigned short Ws[3 * 4096];
    int bx, by, bz;
    swz_bxyz(bx, by, bz);
    int m0 = by << 7, n0 = bx << 7;
    int z = bz;
    int kbeg = z * KC;
    int kc2 = (kbeg + KC > K) ? (K - kbeg) : KC;

    ffrag acc[4][4] = {};
    gemm_core(A, W, M, K, m0, n0, kbeg, kc2 >> 5, As, Ws, acc);

    int tid = threadIdx.x;
    int wave = tid >> 6, lane = tid & 63;
    int cl = lane & 15, qd = lane >> 4;
    int mh = (wave & 1) << 6, nh = (wave >> 1) << 6;
    float* Cz = Pp + (size_t)z * M * N;

    #pragma unroll
    for (int j = 0; j < 4; j++) {
        int col = n0 + nh + (j << 4) + cl;
        float bv = (z == 0) ? bias[col] : 0.0f;
        #pragma unroll
        for (int i = 0; i < 4; i++) {
            int row0 = m0 + mh + (i << 4) + (qd << 2);
            #pragma unroll
            for (int r = 0; r < 4; r++) {
                int row = row0 + r;
                if (row < M)
                    Cz[(size_t)row * N + col] = acc[i][j][r] + bv;
            }
        }
    }
}

// ---------------------------------------------------------------- MFMA flash attention v5
#define LP 72
#define SCL2 0.18033688011112042f   // 0.125 * log2(e)
__global__ __launch_bounds__(256) void attn_kernel(const unsigned short* __restrict__ Qg,
                                                   const unsigned short* __restrict__ Kg,
                                                   const unsigned short* __restrict__ vT,
                                                   const unsigned long long* __restrict__ mtab,
                                                   unsigned short* __restrict__ O) {
    __shared__ unsigned short Ks[64 * LP];     // [k'][d]
    __shared__ unsigned short Vt[80 * LP];     // [d][k']; rows 64..79 = ones row + zeros
    __shared__ unsigned short Pb[64 * LP];     // [q_local][k' block-rotated]
    int tid = threadIdx.x;
    int wave = tid >> 6, lane = tid & 63;
    int cl = lane & 15, qd = lane >> 4;
    int bx, by, bz;
    swz_bxyz(bx, by, bz);                      // group all 13 q-tiles of a head on one XCD
    int bh = by;
    int b = bh / NHEAD, hh = bh % NHEAD;
    int q0 = bx * 64;
    int qw = q0 + wave * 16;

    // ones row (d=64) + zero rows (65..79) for the l-accumulating fragment t=4
    for (int i = tid; i < 16 * LP; i += 256)
        Vt[64 * LP + i] = (i < LP) ? (unsigned short)0x3F80 : (unsigned short)0;

    int qrow = qw + cl;
    if (qrow > TT - 1) qrow = TT - 1;
    const unsigned short* qb = Qg + (size_t)(b * TT + qrow) * EE + hh * 64;
    bfrag qf0 = *(const bfrag*)(qb + (qd << 3));
    bfrag qf1 = *(const bfrag*)(qb + 32 + (qd << 3));

    ffrag o_acc[5] = {};                       // [0..3]=O, [4]=l (ones column)
    float m_run[4];
    int qg_[4], qm_[4];
    #pragma unroll
    for (int r = 0; r < 4; r++) {
        qg_[r] = qw + (qd << 2) + r;
        qm_[r] = qg_[r] > TT - 1 ? TT - 1 : qg_[r];
        m_run[r] = -1e30f;
    }

    const unsigned short* kbase = Kg + (size_t)b * TT * EE + hh * 64;
    const unsigned short* vbase = vT + (size_t)(b * NHEAD + hh) * 64 * TTP;
    int srow = tid >> 3;            // 0..31
    int scol = (tid & 7) << 3;      // 0..56
    int r0 = srow, r1 = 32 + srow;
    const unsigned short* vp0 = vbase + (size_t)r0 * TTP + scol;
    const unsigned short* vp1 = vbase + (size_t)r1 * TTP + scol;

    // prefetch tile 0 into regs
    bfrag kreg0 = *(const bfrag*)(kbase + (size_t)r0 * EE + scol);
    bfrag kreg1 = *(const bfrag*)(kbase + (size_t)r1 * EE + scol);
    bfrag vreg0 = *(const bfrag*)vp0;
    bfrag vreg1 = *(const bfrag*)vp1;

    // P read addresses (undo the per-row block rotation)
    int rot = (cl >> 2) & 3;
    int pread0 = (wave * 16 + cl) * LP + ((((qd >> 1)    ) ^ rot) << 4) + ((qd & 1) << 3);
    int pread1 = (wave * 16 + cl) * LP + (((2 + (qd >> 1)) ^ rot) << 4) + ((qd & 1) << 3);

    for (int k0 = 0; k0 < 832; k0 += 64) {
        __syncthreads();           // all reads of previous tile done
        *(bfrag*)&Ks[r0 * LP + scol] = kreg0;
        *(bfrag*)&Ks[r1 * LP + scol] = kreg1;
        *(bfrag*)&Vt[r0 * LP + scol] = vreg0;
        *(bfrag*)&Vt[r1 * LP + scol] = vreg1;

        // mask bits for this tile (4 x 8B loads, L1/L2-hot 82 KB table)
        int tix = k0 >> 6;
        unsigned mlo[4], mhi[4];
        #pragma unroll
        for (int r = 0; r < 4; r++) {
            unsigned long long mb = mtab[qm_[r] * 13 + tix];
            mlo[r] = (unsigned)mb;
            mhi[r] = (unsigned)(mb >> 32);
        }
        __syncthreads();           // tile staged

        // prefetch next tile into regs (overlaps compute below)
        if (k0 + 64 < 832) {
            int kn = k0 + 64;
            int t0 = kn + r0; if (t0 > TT - 1) t0 = TT - 1;
            int t1 = kn + r1; if (t1 > TT - 1) t1 = TT - 1;
            kreg0 = *(const bfrag*)(kbase + (size_t)t0 * EE + scol);
            kreg1 = *(const bfrag*)(kbase + (size_t)t1 * EE + scol);
            vreg0 = *(const bfrag*)(vp0 + kn);
            vreg1 = *(const bfrag*)(vp1 + kn);
        }

        // S = Q K^T
        ffrag sv[4];
        #pragma unroll
        for (int j = 0; j < 4; j++) {
            bfrag kf0 = *(const bfrag*)&Ks[(j * 16 + cl) * LP + (qd << 3)];
            bfrag kf1 = *(const bfrag*)&Ks[(j * 16 + cl) * LP + 32 + (qd << 3)];
            ffrag z = {0.f, 0.f, 0.f, 0.f};
            z = __builtin_amdgcn_mfma_f32_16x16x32_bf16(qf0, kf0, z, 0, 0, 0);
            z = __builtin_amdgcn_mfma_f32_16x16x32_bf16(qf1, kf1, z, 0, 0, 0);
            sv[j] = z;
        }

        // mask via table bits
        #pragma unroll
        for (int j = 0; j < 4; j++) {
            #pragma unroll
            for (int r = 0; r < 4; r++) {
                unsigned sel = (j < 2) ? mlo[r] : mhi[r];
                if ((sel >> (((j & 1) << 4) + cl)) & 1) sv[j][r] = -3.0e38f;
            }
        }

        // online softmax; l accumulates in o_acc[4] via the ones column
        #pragma unroll
        for (int r = 0; r < 4; r++) {
            float mx = fmaxf(fmaxf(sv[0][r], sv[1][r]), fmaxf(sv[2][r], sv[3][r]));
            mx = fmaxf(mx, __shfl_xor(mx, 1, 64));
            mx = fmaxf(mx, __shfl_xor(mx, 2, 64));
            mx = fmaxf(mx, __shfl_xor(mx, 4, 64));
            mx = fmaxf(mx, __shfl_xor(mx, 8, 64));
            float m_new = fmaxf(m_run[r], mx);
            float alpha = fexp2((m_run[r] - m_new) * SCL2);
            float p0 = fexp2((sv[0][r] - m_new) * SCL2);
            float p1 = fexp2((sv[1][r] - m_new) * SCL2);
            float p2 = fexp2((sv[2][r] - m_new) * SCL2);
            float p3 = fexp2((sv[3][r] - m_new) * SCL2);
            m_run[r] = m_new;
            #pragma unroll
            for (int t = 0; t < 5; t++) o_acc[t][r] *= alpha;
            int prow = (wave * 16 + (qd << 2) + r) * LP;
            Pb[prow + ((0 ^ qd) << 4) + cl] = f2b(p0);   // block-rotated store:
            Pb[prow + ((1 ^ qd) << 4) + cl] = f2b(p1);   // disjoint bank windows
            Pb[prow + ((2 ^ qd) << 4) + cl] = f2b(p2);   // per qd group
            Pb[prow + ((3 ^ qd) << 4) + cl] = f2b(p3);
        }
        // Pb rows are wave-private: drain this wave's LDS writes only
        asm volatile("s_waitcnt lgkmcnt(0)" ::: "memory");

        // O += P @ V  (t=4 accumulates l against the ones row)
        bfrag pf0 = *(const bfrag*)&Pb[pread0];
        bfrag pf1 = *(const bfrag*)&Pb[pread1];
        #pragma unroll
        for (int t = 0; t < 5; t++) {
            bfrag vf0 = *(const bfrag*)&Vt[(t * 16 + cl) * LP + (qd << 3)];
            bfrag vf1 = *(const bfrag*)&Vt[(t * 16 + cl) * LP + 32 + (qd << 3)];
            o_acc[t] = __builtin_amdgcn_mfma_f32_16x16x32_bf16(pf0, vf0, o_acc[t], 0, 0, 0);
            o_acc[t] = __builtin_amdgcn_mfma_f32_16x16x32_bf16(pf1, vf1, o_acc[t], 0, 0, 0);
        }
    }

    #pragma unroll
    for (int r = 0; r < 4; r++) {
        // l lives in column 0 of fragment 4 -> lanes qd*16; broadcast within group
        float l = __shfl(o_acc[4][r], lane & 48, 64);
        float inv = frcp(fmaxf(l, 1e-30f));
        if (qg_[r] < TT) {
            #pragma unroll
            for (int t = 0; t < 4; t++)
                O[(size_t)(b * TT + qg_[r]) * EE + hh * 64 + t * 16 + cl] =
                    f2b(o_acc[t][r] * inv);
        }
    }
}

// ---------------------------------------------------------------- head
__global__ __launch_bounds__(256) void head_kernel(const float* __restrict__ Y,
                                                   const float* __restrict__ hw,
                                                   const float* __restrict__ hb,
                                                   const float* __restrict__ mean_,
                                                   const float* __restrict__ std_,
                                                   float* __restrict__ out) {
    __shared__ float sb[4];
    int row = blockIdx.x;
    int tid = threadIdx.x;
    const float* y = Y + (size_t)row * EE;
    float v = y[tid] * hw[tid] + y[tid + 256] * hw[tid + 256] + y[tid + 512] * hw[tid + 512];
    v = block_reduce_sum256(v, sb);
    if (tid == 0) {
        float logit = v + hb[0];
        float z = logit * std_[0] + mean_[0];
        float f = expf(z * 2.302585092994046f) - 1e-8f;
        f = fminf(fmaxf(f, 1e-15f), 1.0f);
        out[4 + row] = f;
    }
}

__global__ __launch_bounds__(256) void flux_sum_kernel(float* __restrict__ out) {
    __shared__ float sb[4];
    int b = blockIdx.x;
    int tid = threadIdx.x;
    const float* pf = out + 4 + (size_t)b * TT;
    float v = pf[tid] + pf[tid + 256] + pf[tid + 512];
    if (tid < TT - 768) v += pf[tid + 768];
    v = block_reduce_sum256(v, sb);
    if (tid == 0) out[b] = fmaxf(v, 1e-15f);
}

// ---------------------------------------------------------------- host
extern "C" void kernel_launch(void* const* d_in, const int* in_sizes, int n_in,
                              void* d_out, int out_size, void* d_ws, size_t ws_size,
                              hipStream_t stream) {
    const float* x        = (const float*)d_in[0];
    const float* sxr_mean = (const float*)d_in[1];
    const float* sxr_std  = (const float*)d_in[2];
    const float* input_w  = (const float*)d_in[3];
    const float* input_b  = (const float*)d_in[4];
    const float* pos_emb  = (const float*)d_in[5];
    const float* ln1_w    = (const float*)d_in[6];
    const float* ln1_b    = (const float*)d_in[7];
    const float* in_w     = (const float*)d_in[8];
    const float* in_b     = (const float*)d_in[9];
    const float* out_w    = (const float*)d_in[10];
    const float* out_b    = (const float*)d_in[11];
    const float* ln2_w    = (const float*)d_in[12];
    const float* ln2_b    = (const float*)d_in[13];
    const float* w1       = (const float*)d_in[14];
    const float* b1       = (const float*)d_in[15];
    const float* w2       = (const float*)d_in[16];
    const float* b2       = (const float*)d_in[17];
    const float* head_ln_w = (const float*)d_in[18];
    const float* head_ln_b = (const float*)d_in[19];
    const float* head_w   = (const float*)d_in[20];
    const float* head_b   = (const float*)d_in[21];
    float* out = (float*)d_out;

    const size_t NROW = (size_t)BB * TT;               // 3136
    const size_t NE   = NROW * EE;

    float* h   = (float*)d_ws;                         // [3136,768] f32
    float* y32 = h + NE;                               // [3136,768] f32 (head only)
    unsigned short* q_b   = (unsigned short*)(y32 + NE);   // [3136,768] bf16
    unsigned short* k_b   = q_b + NE;                      // [3136,768] bf16
    unsigned short* vT_b  = k_b + NE;                      // [48*64, 832] bf16
    unsigned short* y_b   = vT_b + (size_t)BB * NHEAD * 64 * TTP;
    unsigned short* o_b   = y_b + NE;
    unsigned short* mlp_b = o_b + NE;                  // [3136,3072] bf16
    unsigned short* wq_b  = mlp_b + NROW * HDIM;
    unsigned short* wo_b  = wq_b + (size_t)3 * EE * EE;
    unsigned short* w1_b  = wo_b + (size_t)EE * EE;
    unsigned short* w2_b  = w1_b + (size_t)HDIM * EE;
    unsigned long long* mtab = (unsigned long long*)(w2_b + (size_t)EE * HDIM);  // [784*13] u64
    float* Pp = (float*)(mtab + TT * 13);              // [4][3136*768] f32 partials

    const int tot = BB * TT * EE;
    const int GY = (int)((NROW + 127) / 128);          // 25

    patchify_kernel<<<(tot + 255) / 256, 256, 0, stream>>>(x, mlp_b);
    cast_kernel<<<(EE * EE / 4 + 255) / 256, 256, 0, stream>>>(input_w, wo_b, EE * EE / 4);
    posfill_kernel<<<(tot + 255) / 256, 256, 0, stream>>>(h, pos_emb);
    mask_build_kernel<<<(TT * 13 + 255) / 256, 256, 0, stream>>>(mtab);
    gemm_bf16_pk<<<dim3(EE / 128, GY, 4), 256, 0, stream>>>(
        mlp_b, wo_b, input_b, Pp, (int)NROW, EE, EE, 192);

    for (int l = 0; l < NLAYER; l++) {
        fused_cast_kernel<<<6912, 256, 0, stream>>>(
            in_w + (size_t)l * 3 * EE * EE, out_w + (size_t)l * EE * EE,
            w1 + (size_t)l * HDIM * EE, w2 + (size_t)l * EE * HDIM,
            wq_b, wo_b, w1_b, w2_b);

        // h += partials (embed or previous W2); y = LN1(h)
        ln_red_kernel<<<(int)NROW, 192, 0, stream>>>(
            h, Pp, ln1_w + l * EE, ln1_b + l * EE, y_b, nullptr);
        gemm_qkv<<<dim3(3 * EE / 128, GY), 256, 0, stream>>>(
            y_b, wq_b, in_b + (size_t)l * 3 * EE, q_b, k_b, vT_b,
            (int)NROW, 3 * EE, EE);
        attn_kernel<<<dim3(13, BB * NHEAD), 256, 0, stream>>>(q_b, k_b, vT_b, mtab, o_b);
        gemm_bf16_pk<<<dim3(EE / 128, GY, 4), 256, 0, stream>>>(
            o_b, wo_b, out_b + (size_t)l * EE, Pp, (int)NROW, EE, EE, 192);
        // h += out-proj partials; y = LN2(h)
        ln_red_kernel<<<(int)NROW, 192, 0, stream>>>(
            h, Pp, ln2_w + l * EE, ln2_b + l * EE, y_b, nullptr);
        gemm_bf16<<<dim3(HDIM / 128, GY), 256, 0, stream>>>(
            y_b, w1_b, b1 + (size_t)l * HDIM, nullptr, nullptr, mlp_b,
            (int)NROW, HDIM, EE, 1);
        gemm_bf16_pk<<<dim3(EE / 128, GY, 4), 256, 0, stream>>>(
            mlp_b, w2_b, b2 + (size_t)l * EE, Pp, (int)NROW, EE, HDIM, 768);
    }

    // h += final W2 partials; y = head LN(h) (bf16 + f32)
    ln_red_kernel<<<(int)NROW, 192, 0, stream>>>(
        h, Pp, head_ln_w, head_ln_b, y_b, y32);
    head_kernel<<<(int)NROW, 256, 0, stream>>>(y32, head_w, head_b, sxr_mean, sxr_std, out);
    flux_sum_kernel<<<BB, 256, 0, stream>>>(out);
}